// Round 1
// baseline (885.400 us; speedup 1.0000x reference)
//
#include <hip/hip_runtime.h>

#define NN 100000
#define EE 1600000
#define DIM 128

// ---------------- degree ----------------
__global__ void k_deg(const int* __restrict__ dst, int* __restrict__ deg) {
  int i = blockIdx.x * blockDim.x + threadIdx.x;
  int st = gridDim.x * blockDim.x;
  for (int e = i; e < EE; e += st) atomicAdd(&deg[dst[e]], 1);
}

__global__ void k_dsqrt(const int* __restrict__ deg, float* __restrict__ ds) {
  int i = blockIdx.x * blockDim.x + threadIdx.x;
  if (i < NN) ds[i] = rsqrtf(fmaxf((float)deg[i], 1.0f));
}

// ---------------- single-block exclusive scan -> row_ptr ----------------
__global__ __launch_bounds__(1024) void k_scan(const int* __restrict__ deg,
                                               int* __restrict__ rp) {
  __shared__ int ps[1024];
  int t = threadIdx.x;
  const int chunk = (NN + 1023) / 1024;  // 98
  int beg = t * chunk;
  if (beg > NN) beg = NN;
  int end = beg + chunk;
  if (end > NN) end = NN;
  int s = 0;
  for (int i = beg; i < end; ++i) s += deg[i];
  ps[t] = s;
  __syncthreads();
  for (int off = 1; off < 1024; off <<= 1) {
    int v = (t >= off) ? ps[t - off] : 0;
    __syncthreads();
    ps[t] += v;
    __syncthreads();
  }
  int run = ps[t] - s;  // exclusive prefix
  for (int i = beg; i < end; ++i) { rp[i] = run; run += deg[i]; }
  if (end == NN) rp[NN] = run;  // all threads past the end write the same total
}

// ---------------- scatter edges into CSR order ----------------
__global__ void k_scatter(const int* __restrict__ src, const int* __restrict__ dst,
                          const int* __restrict__ rp, int* __restrict__ cnt,
                          int* __restrict__ esrc) {
  int i = blockIdx.x * blockDim.x + threadIdx.x;
  int st = gridDim.x * blockDim.x;
  for (int e = i; e < EE; e += st) {
    int d = dst[e];
    int pos = rp[d] + atomicAdd(&cnt[d], 1);
    esrc[pos] = src[e];
  }
}

// ---------------- propagation: out[n] = alpha*ds[n]*sum_{s in in(n)} X[s]*ds[s] (- Xb[n]) ----
__global__ __launch_bounds__(128) void k_prop(const float* __restrict__ X,
                                              const float* __restrict__ ds,
                                              const int* __restrict__ rp,
                                              const int* __restrict__ esrc,
                                              const float* __restrict__ Xb,
                                              float alpha,
                                              float* __restrict__ out) {
  int n = blockIdx.x;
  int t = threadIdx.x;
  int beg = rp[n], end = rp[n + 1];
  float acc = 0.f;
  for (int p = beg; p < end; ++p) {
    int s = esrc[p];
    acc = fmaf(X[(size_t)s * DIM + t], ds[s], acc);
  }
  float v = alpha * ds[n] * acc;
  if (Xb) v -= Xb[(size_t)n * DIM + t];
  out[(size_t)n * DIM + t] = v;
}

// ---------------- GEMM: h = [X0|X1|X2] @ W + bias, h *= snorm; col sums for BN ----
__global__ __launch_bounds__(256) void k_gemm(const float* __restrict__ X0f,
                                              const float* __restrict__ X1,
                                              const float* __restrict__ X2,
                                              const float* __restrict__ W,
                                              const float* __restrict__ bias,
                                              const float* __restrict__ snorm,
                                              float* __restrict__ out,
                                              float* __restrict__ gsum,
                                              float* __restrict__ gsq) {
  __shared__ float Xs[128][68];   // 128 nodes x 64 k, padded (+4) to break bank stride
  __shared__ float Ws[64][128];   // 64 k x 128 cols
  __shared__ float ls[256];       // [0..127] col sums, [128..255] col sumsq
  int tid = threadIdx.x;
  int tx = tid & 15;   // cols 4*tx..4*tx+3 and 64+4*tx..64+4*tx+3
  int ty = tid >> 4;   // rows ty + 16*m, m = 0..7
  int node0 = blockIdx.x * 128;

  float acc[8][8];
  #pragma unroll
  for (int m = 0; m < 8; ++m)
    #pragma unroll
    for (int j = 0; j < 8; ++j) acc[m][j] = 0.f;

  const float* srcs[3] = {X0f, X1, X2};
  for (int c = 0; c < 6; ++c) {
    const float* A = srcs[c >> 1];
    int koff = (c & 1) * 64;
    __syncthreads();
    // stage X tile: 128 rows x 16 float4
    #pragma unroll
    for (int l = 0; l < 8; ++l) {
      int it = tid + l * 256;
      int r = it >> 4, c4 = it & 15;
      int row = node0 + r;
      if (row >= NN) row = NN - 1;
      *(float4*)&Xs[r][c4 * 4] =
          *(const float4*)(A + (size_t)row * DIM + koff + c4 * 4);
    }
    // stage W tile: contiguous 32KB
    const float4* Wg = (const float4*)(W + (size_t)c * 64 * DIM);
    #pragma unroll
    for (int l = 0; l < 8; ++l) {
      int it = tid + l * 256;
      ((float4*)Ws)[it] = Wg[it];
    }
    __syncthreads();
    #pragma unroll 2
    for (int kk = 0; kk < 64; ++kk) {
      float4 w0 = *(const float4*)&Ws[kk][4 * tx];
      float4 w1 = *(const float4*)&Ws[kk][64 + 4 * tx];
      float xr[8];
      #pragma unroll
      for (int m = 0; m < 8; ++m) xr[m] = Xs[ty + 16 * m][kk];
      #pragma unroll
      for (int m = 0; m < 8; ++m) {
        acc[m][0] = fmaf(xr[m], w0.x, acc[m][0]);
        acc[m][1] = fmaf(xr[m], w0.y, acc[m][1]);
        acc[m][2] = fmaf(xr[m], w0.z, acc[m][2]);
        acc[m][3] = fmaf(xr[m], w0.w, acc[m][3]);
        acc[m][4] = fmaf(xr[m], w1.x, acc[m][4]);
        acc[m][5] = fmaf(xr[m], w1.y, acc[m][5]);
        acc[m][6] = fmaf(xr[m], w1.z, acc[m][6]);
        acc[m][7] = fmaf(xr[m], w1.w, acc[m][7]);
      }
    }
  }

  float4 b0 = *(const float4*)(bias + 4 * tx);
  float4 b1 = *(const float4*)(bias + 64 + 4 * tx);
  float cs[8], cq[8];
  #pragma unroll
  for (int j = 0; j < 8; ++j) { cs[j] = 0.f; cq[j] = 0.f; }
  #pragma unroll
  for (int m = 0; m < 8; ++m) {
    int row = node0 + ty + 16 * m;
    if (row < NN) {
      float sn = snorm[row];
      float h0 = (acc[m][0] + b0.x) * sn;
      float h1 = (acc[m][1] + b0.y) * sn;
      float h2 = (acc[m][2] + b0.z) * sn;
      float h3 = (acc[m][3] + b0.w) * sn;
      float h4 = (acc[m][4] + b1.x) * sn;
      float h5 = (acc[m][5] + b1.y) * sn;
      float h6 = (acc[m][6] + b1.z) * sn;
      float h7 = (acc[m][7] + b1.w) * sn;
      *(float4*)(out + (size_t)row * DIM + 4 * tx) = make_float4(h0, h1, h2, h3);
      *(float4*)(out + (size_t)row * DIM + 64 + 4 * tx) = make_float4(h4, h5, h6, h7);
      cs[0] += h0; cq[0] += h0 * h0;
      cs[1] += h1; cq[1] += h1 * h1;
      cs[2] += h2; cq[2] += h2 * h2;
      cs[3] += h3; cq[3] += h3 * h3;
      cs[4] += h4; cq[4] += h4 * h4;
      cs[5] += h5; cq[5] += h5 * h5;
      cs[6] += h6; cq[6] += h6 * h6;
      cs[7] += h7; cq[7] += h7 * h7;
    }
  }
  __syncthreads();
  ls[tid] = 0.f;
  __syncthreads();
  #pragma unroll
  for (int j = 0; j < 4; ++j) {
    atomicAdd(&ls[4 * tx + j], cs[j]);
    atomicAdd(&ls[64 + 4 * tx + j], cs[4 + j]);
    atomicAdd(&ls[128 + 4 * tx + j], cq[j]);
    atomicAdd(&ls[128 + 64 + 4 * tx + j], cq[4 + j]);
  }
  __syncthreads();
  if (tid < 128) {
    atomicAdd(&gsum[tid], ls[tid]);
    atomicAdd(&gsq[tid], ls[128 + tid]);
  }
}

// ---------------- BN prep + apply ----------------
__global__ void k_bnprep(const float* __restrict__ gsum, const float* __restrict__ gsq,
                         const float* __restrict__ gamma, const float* __restrict__ beta,
                         float* __restrict__ scale, float* __restrict__ shift) {
  int c = threadIdx.x;
  if (c < DIM) {
    float mean = gsum[c] * (1.0f / NN);
    float var = gsq[c] * (1.0f / NN) - mean * mean;
    var = fmaxf(var, 0.f);
    float sc = gamma[c] * rsqrtf(var + 1e-5f);
    scale[c] = sc;
    shift[c] = beta[c] - mean * sc;
  }
}

__global__ void k_apply(float* __restrict__ out, const float* __restrict__ scale,
                        const float* __restrict__ shift) {
  const int total4 = NN * DIM / 4;  // 3,200,000
  int i = blockIdx.x * blockDim.x + threadIdx.x;
  int st = gridDim.x * blockDim.x;
  for (int i4 = i; i4 < total4; i4 += st) {
    int c4 = (i4 & 31) * 4;
    float4 v = ((float4*)out)[i4];
    float4 s = *(const float4*)(scale + c4);
    float4 sh = *(const float4*)(shift + c4);
    v.x = fmaxf(fmaf(v.x, s.x, sh.x), 0.f);
    v.y = fmaxf(fmaf(v.y, s.y, sh.y), 0.f);
    v.z = fmaxf(fmaf(v.z, s.z, sh.z), 0.f);
    v.w = fmaxf(fmaf(v.w, s.w, sh.w), 0.f);
    ((float4*)out)[i4] = v;
  }
}

extern "C" void kernel_launch(void* const* d_in, const int* in_sizes, int n_in,
                              void* d_out, int out_size, void* d_ws, size_t ws_size,
                              hipStream_t stream) {
  const float* feature = (const float*)d_in[0];
  const float* snorm   = (const float*)d_in[1];
  const int*   src     = (const int*)d_in[2];
  const int*   dst     = (const int*)d_in[3];
  const float* W       = (const float*)d_in[4];
  const float* bias    = (const float*)d_in[5];
  const float* gamma   = (const float*)d_in[6];
  const float* beta    = (const float*)d_in[7];
  float* out = (float*)d_out;

  char* p = (char*)d_ws;
  float* X1 = (float*)p;  p += (size_t)NN * DIM * 4;       // 51.2 MB
  float* X2 = (float*)p;  p += (size_t)NN * DIM * 4;       // 51.2 MB
  int* esrc = (int*)p;    p += (size_t)EE * 4;             // 6.4 MB
  int* rp   = (int*)p;    p += ((size_t)(NN + 1) * 4 + 127) & ~(size_t)127;
  float* ds = (float*)p;  p += (size_t)NN * 4;
  char* zbeg = p;                                          // zeroed region start
  int* deg  = (int*)p;    p += (size_t)NN * 4;
  int* cnt  = (int*)p;    p += (size_t)NN * 4;
  float* gsum = (float*)p; p += 512;
  float* gsq  = (float*)p; p += 512;
  float* scale = (float*)p; p += 512;
  float* shift = (float*)p; p += 512;

  hipMemsetAsync(zbeg, 0, (size_t)NN * 8 + 1024, stream);  // deg, cnt, gsum, gsq

  k_deg<<<2048, 256, 0, stream>>>(dst, deg);
  k_dsqrt<<<(NN + 255) / 256, 256, 0, stream>>>(deg, ds);
  k_scan<<<1, 1024, 0, stream>>>(deg, rp);
  k_scatter<<<2048, 256, 0, stream>>>(src, dst, rp, cnt, esrc);
  k_prop<<<NN, 128, 0, stream>>>(feature, ds, rp, esrc, nullptr, -1.0f, X1);
  k_prop<<<NN, 128, 0, stream>>>(X1, ds, rp, esrc, feature, -2.0f, X2);
  k_gemm<<<(NN + 127) / 128, 256, 0, stream>>>(feature, X1, X2, W, bias, snorm,
                                               out, gsum, gsq);
  k_bnprep<<<1, 128, 0, stream>>>(gsum, gsq, gamma, beta, scale, shift);
  k_apply<<<4096, 256, 0, stream>>>(out, scale, shift);
}

// Round 2
// 688.132 us; speedup vs baseline: 1.2867x; 1.2867x over previous
//
#include <hip/hip_runtime.h>

#define NN 100000
#define EE 1600000
#define DIM 128

typedef unsigned int u32;

__device__ __forceinline__ float lof(u32 u) { return __uint_as_float(u << 16); }
__device__ __forceinline__ float hif(u32 u) { return __uint_as_float(u & 0xffff0000u); }
__device__ __forceinline__ u32 pack_bf2(float a, float b) {
  u32 ua = __float_as_uint(a), ub = __float_as_uint(b);
  ua = (ua + 0x7fffu + ((ua >> 16) & 1u)) >> 16;
  ub = (ub + 0x7fffu + ((ub >> 16) & 1u)) & 0xffff0000u;
  return ua | ub;
}

// ---------------- degree ----------------
__global__ void k_deg(const int* __restrict__ dst, int* __restrict__ deg) {
  int i = blockIdx.x * blockDim.x + threadIdx.x;
  int st = gridDim.x * blockDim.x;
  for (int e = i; e < EE; e += st) atomicAdd(&deg[dst[e]], 1);
}

__global__ void k_dsqrt(const int* __restrict__ deg, float* __restrict__ ds) {
  int i = blockIdx.x * blockDim.x + threadIdx.x;
  if (i < NN) ds[i] = rsqrtf(fmaxf((float)deg[i], 1.0f));
}

// ---------------- single-block exclusive scan -> row_ptr ----------------
__global__ __launch_bounds__(1024) void k_scan(const int* __restrict__ deg,
                                               int* __restrict__ rp) {
  __shared__ int ps[1024];
  int t = threadIdx.x;
  const int chunk = (NN + 1023) / 1024;  // 98
  int beg = t * chunk;
  if (beg > NN) beg = NN;
  int end = beg + chunk;
  if (end > NN) end = NN;
  int s = 0;
  for (int i = beg; i < end; ++i) s += deg[i];
  ps[t] = s;
  __syncthreads();
  for (int off = 1; off < 1024; off <<= 1) {
    int v = (t >= off) ? ps[t - off] : 0;
    __syncthreads();
    ps[t] += v;
    __syncthreads();
  }
  int run = ps[t] - s;  // exclusive prefix
  for (int i = beg; i < end; ++i) { rp[i] = run; run += deg[i]; }
  if (end == NN) rp[NN] = run;
}

// ---------------- scatter edges into CSR order ----------------
__global__ void k_scatter(const int* __restrict__ src, const int* __restrict__ dst,
                          const int* __restrict__ rp, int* __restrict__ cnt,
                          int* __restrict__ esrc) {
  int i = blockIdx.x * blockDim.x + threadIdx.x;
  int st = gridDim.x * blockDim.x;
  for (int e = i; e < EE; e += st) {
    int d = dst[e];
    int pos = rp[d] + atomicAdd(&cnt[d], 1);
    esrc[pos] = src[e];
  }
}

// ---------------- prep: X0b = bf16(feature), Y0 = bf16(feature*ds) ----------------
__global__ void k_prep(const float* __restrict__ feature, const float* __restrict__ ds,
                       u32* __restrict__ X0b, u32* __restrict__ Y0) {
  const int total = NN * 32;  // uint2 count (4 dims each)
  int i = blockIdx.x * blockDim.x + threadIdx.x;
  int st = gridDim.x * blockDim.x;
  for (int j = i; j < total; j += st) {
    int n = j >> 5;
    float4 f = *(const float4*)(feature + (size_t)n * DIM + (j & 31) * 4);
    float dsn = ds[n];
    ((uint2*)X0b)[j] = make_uint2(pack_bf2(f.x, f.y), pack_bf2(f.z, f.w));
    ((uint2*)Y0)[j] = make_uint2(pack_bf2(f.x * dsn, f.y * dsn),
                                 pack_bf2(f.z * dsn, f.w * dsn));
  }
}

// ---------------- prop1: X1 = -ds[n]*sum Y0[s]; write X1b, Y1 = X1*ds[n] ----------------
__global__ __launch_bounds__(256) void k_prop1(const u32* __restrict__ Y0,
                                               const float* __restrict__ ds,
                                               const int* __restrict__ rp,
                                               const int* __restrict__ esrc,
                                               u32* __restrict__ X1b,
                                               u32* __restrict__ Y1) {
  int n = blockIdx.x * 4 + (threadIdx.x >> 6);
  int l = threadIdx.x & 63;
  int beg = rp[n], end = rp[n + 1];
  float a0x = 0, a0y = 0, a1x = 0, a1y = 0, a2x = 0, a2y = 0, a3x = 0, a3y = 0;
  int p = beg;
  for (; p + 4 <= end; p += 4) {
    int s0 = esrc[p], s1 = esrc[p + 1], s2 = esrc[p + 2], s3 = esrc[p + 3];
    u32 u0 = Y0[(size_t)s0 * 64 + l];
    u32 u1 = Y0[(size_t)s1 * 64 + l];
    u32 u2 = Y0[(size_t)s2 * 64 + l];
    u32 u3 = Y0[(size_t)s3 * 64 + l];
    a0x += lof(u0); a0y += hif(u0);
    a1x += lof(u1); a1y += hif(u1);
    a2x += lof(u2); a2y += hif(u2);
    a3x += lof(u3); a3y += hif(u3);
  }
  for (; p < end; ++p) {
    u32 u = Y0[(size_t)esrc[p] * 64 + l];
    a0x += lof(u); a0y += hif(u);
  }
  float dsn = ds[n];
  float x = -dsn * ((a0x + a1x) + (a2x + a3x));
  float y = -dsn * ((a0y + a1y) + (a2y + a3y));
  X1b[(size_t)n * 64 + l] = pack_bf2(x, y);
  Y1[(size_t)n * 64 + l] = pack_bf2(x * dsn, y * dsn);
}

// ---------------- prop2: X2 = -2*ds[n]*sum Y1[s] - X0 ----------------
__global__ __launch_bounds__(256) void k_prop2(const u32* __restrict__ Y1,
                                               const u32* __restrict__ X0b,
                                               const float* __restrict__ ds,
                                               const int* __restrict__ rp,
                                               const int* __restrict__ esrc,
                                               u32* __restrict__ X2b) {
  int n = blockIdx.x * 4 + (threadIdx.x >> 6);
  int l = threadIdx.x & 63;
  int beg = rp[n], end = rp[n + 1];
  float a0x = 0, a0y = 0, a1x = 0, a1y = 0, a2x = 0, a2y = 0, a3x = 0, a3y = 0;
  int p = beg;
  for (; p + 4 <= end; p += 4) {
    int s0 = esrc[p], s1 = esrc[p + 1], s2 = esrc[p + 2], s3 = esrc[p + 3];
    u32 u0 = Y1[(size_t)s0 * 64 + l];
    u32 u1 = Y1[(size_t)s1 * 64 + l];
    u32 u2 = Y1[(size_t)s2 * 64 + l];
    u32 u3 = Y1[(size_t)s3 * 64 + l];
    a0x += lof(u0); a0y += hif(u0);
    a1x += lof(u1); a1y += hif(u1);
    a2x += lof(u2); a2y += hif(u2);
    a3x += lof(u3); a3y += hif(u3);
  }
  for (; p < end; ++p) {
    u32 u = Y1[(size_t)esrc[p] * 64 + l];
    a0x += lof(u); a0y += hif(u);
  }
  float dsn = ds[n];
  u32 u0 = X0b[(size_t)n * 64 + l];
  float x = -2.0f * dsn * ((a0x + a1x) + (a2x + a3x)) - lof(u0);
  float y = -2.0f * dsn * ((a0y + a1y) + (a2y + a3y)) - hif(u0);
  X2b[(size_t)n * 64 + l] = pack_bf2(x, y);
}

// ---------------- GEMM: h = [X0|X1|X2] @ W + bias, h *= snorm; col sums for BN ----
__global__ __launch_bounds__(256) void k_gemm(const u32* __restrict__ X0b,
                                              const u32* __restrict__ X1b,
                                              const u32* __restrict__ X2b,
                                              const float* __restrict__ W,
                                              const float* __restrict__ bias,
                                              const float* __restrict__ snorm,
                                              float* __restrict__ out,
                                              float* __restrict__ gsum,
                                              float* __restrict__ gsq) {
  __shared__ float Xs[128][72];   // 128 nodes x 64 k (pad 72 keeps float4 align)
  __shared__ float Ws[64][128];   // 64 k x 128 cols
  __shared__ float ls[256];       // [0..127] col sums, [128..255] col sumsq
  int tid = threadIdx.x;
  int tx = tid & 15;
  int ty = tid >> 4;
  int node0 = blockIdx.x * 128;

  float acc[8][8];
  #pragma unroll
  for (int m = 0; m < 8; ++m)
    #pragma unroll
    for (int j = 0; j < 8; ++j) acc[m][j] = 0.f;

  const u32* srcs[3] = {X0b, X1b, X2b};
  for (int c = 0; c < 6; ++c) {
    const u32* A = srcs[c >> 1];
    int koff8 = (c & 1) * 8;  // uint4 offset within 16-uint4 row
    __syncthreads();
    // stage X tile: 128 rows x 8 uint4 (bf16x8 each) -> fp32 in LDS
    #pragma unroll
    for (int l = 0; l < 4; ++l) {
      int it = tid + l * 256;
      int r = it >> 3, k4 = it & 7;
      int row = node0 + r;
      if (row >= NN) row = NN - 1;
      uint4 q = *(const uint4*)(A + (size_t)row * 64 + (size_t)(koff8 + k4) * 4);
      float* dstp = &Xs[r][k4 * 8];
      ((float4*)dstp)[0] = make_float4(lof(q.x), hif(q.x), lof(q.y), hif(q.y));
      ((float4*)dstp)[1] = make_float4(lof(q.z), hif(q.z), lof(q.w), hif(q.w));
    }
    // stage W tile: contiguous 32KB
    const float4* Wg = (const float4*)(W + (size_t)c * 64 * DIM);
    #pragma unroll
    for (int l = 0; l < 8; ++l) {
      int it = tid + l * 256;
      ((float4*)Ws)[it] = Wg[it];
    }
    __syncthreads();
    #pragma unroll 2
    for (int kk = 0; kk < 64; ++kk) {
      float4 w0 = *(const float4*)&Ws[kk][4 * tx];
      float4 w1 = *(const float4*)&Ws[kk][64 + 4 * tx];
      float xr[8];
      #pragma unroll
      for (int m = 0; m < 8; ++m) xr[m] = Xs[ty + 16 * m][kk];
      #pragma unroll
      for (int m = 0; m < 8; ++m) {
        acc[m][0] = fmaf(xr[m], w0.x, acc[m][0]);
        acc[m][1] = fmaf(xr[m], w0.y, acc[m][1]);
        acc[m][2] = fmaf(xr[m], w0.z, acc[m][2]);
        acc[m][3] = fmaf(xr[m], w0.w, acc[m][3]);
        acc[m][4] = fmaf(xr[m], w1.x, acc[m][4]);
        acc[m][5] = fmaf(xr[m], w1.y, acc[m][5]);
        acc[m][6] = fmaf(xr[m], w1.z, acc[m][6]);
        acc[m][7] = fmaf(xr[m], w1.w, acc[m][7]);
      }
    }
  }

  float4 b0 = *(const float4*)(bias + 4 * tx);
  float4 b1 = *(const float4*)(bias + 64 + 4 * tx);
  float cs[8], cq[8];
  #pragma unroll
  for (int j = 0; j < 8; ++j) { cs[j] = 0.f; cq[j] = 0.f; }
  #pragma unroll
  for (int m = 0; m < 8; ++m) {
    int row = node0 + ty + 16 * m;
    if (row < NN) {
      float sn = snorm[row];
      float h0 = (acc[m][0] + b0.x) * sn;
      float h1 = (acc[m][1] + b0.y) * sn;
      float h2 = (acc[m][2] + b0.z) * sn;
      float h3 = (acc[m][3] + b0.w) * sn;
      float h4 = (acc[m][4] + b1.x) * sn;
      float h5 = (acc[m][5] + b1.y) * sn;
      float h6 = (acc[m][6] + b1.z) * sn;
      float h7 = (acc[m][7] + b1.w) * sn;
      *(float4*)(out + (size_t)row * DIM + 4 * tx) = make_float4(h0, h1, h2, h3);
      *(float4*)(out + (size_t)row * DIM + 64 + 4 * tx) = make_float4(h4, h5, h6, h7);
      cs[0] += h0; cq[0] += h0 * h0;
      cs[1] += h1; cq[1] += h1 * h1;
      cs[2] += h2; cq[2] += h2 * h2;
      cs[3] += h3; cq[3] += h3 * h3;
      cs[4] += h4; cq[4] += h4 * h4;
      cs[5] += h5; cq[5] += h5 * h5;
      cs[6] += h6; cq[6] += h6 * h6;
      cs[7] += h7; cq[7] += h7 * h7;
    }
  }
  __syncthreads();
  ls[tid] = 0.f;
  __syncthreads();
  #pragma unroll
  for (int j = 0; j < 4; ++j) {
    atomicAdd(&ls[4 * tx + j], cs[j]);
    atomicAdd(&ls[64 + 4 * tx + j], cs[4 + j]);
    atomicAdd(&ls[128 + 4 * tx + j], cq[j]);
    atomicAdd(&ls[128 + 64 + 4 * tx + j], cq[4 + j]);
  }
  __syncthreads();
  if (tid < 128) {
    atomicAdd(&gsum[tid], ls[tid]);
    atomicAdd(&gsq[tid], ls[128 + tid]);
  }
}

// ---------------- BN prep + apply ----------------
__global__ void k_bnprep(const float* __restrict__ gsum, const float* __restrict__ gsq,
                         const float* __restrict__ gamma, const float* __restrict__ beta,
                         float* __restrict__ scale, float* __restrict__ shift) {
  int c = threadIdx.x;
  if (c < DIM) {
    float mean = gsum[c] * (1.0f / NN);
    float var = gsq[c] * (1.0f / NN) - mean * mean;
    var = fmaxf(var, 0.f);
    float sc = gamma[c] * rsqrtf(var + 1e-5f);
    scale[c] = sc;
    shift[c] = beta[c] - mean * sc;
  }
}

__global__ void k_apply(float* __restrict__ out, const float* __restrict__ scale,
                        const float* __restrict__ shift) {
  const int total4 = NN * DIM / 4;
  int i = blockIdx.x * blockDim.x + threadIdx.x;
  int st = gridDim.x * blockDim.x;
  for (int i4 = i; i4 < total4; i4 += st) {
    int c4 = (i4 & 31) * 4;
    float4 v = ((float4*)out)[i4];
    float4 s = *(const float4*)(scale + c4);
    float4 sh = *(const float4*)(shift + c4);
    v.x = fmaxf(fmaf(v.x, s.x, sh.x), 0.f);
    v.y = fmaxf(fmaf(v.y, s.y, sh.y), 0.f);
    v.z = fmaxf(fmaf(v.z, s.z, sh.z), 0.f);
    v.w = fmaxf(fmaf(v.w, s.w, sh.w), 0.f);
    ((float4*)out)[i4] = v;
  }
}

extern "C" void kernel_launch(void* const* d_in, const int* in_sizes, int n_in,
                              void* d_out, int out_size, void* d_ws, size_t ws_size,
                              hipStream_t stream) {
  const float* feature = (const float*)d_in[0];
  const float* snorm   = (const float*)d_in[1];
  const int*   src     = (const int*)d_in[2];
  const int*   dst     = (const int*)d_in[3];
  const float* W       = (const float*)d_in[4];
  const float* bias    = (const float*)d_in[5];
  const float* gamma   = (const float*)d_in[6];
  const float* beta    = (const float*)d_in[7];
  float* out = (float*)d_out;

  const size_t TBL = (size_t)NN * 64 * sizeof(u32);  // 25.6 MB
  char* p = (char*)d_ws;
  u32* X0b = (u32*)p; p += TBL;
  u32* Y0  = (u32*)p; p += TBL;   // reused as X2b after prop1 consumes it
  u32* X1b = (u32*)p; p += TBL;
  u32* Y1  = (u32*)p; p += TBL;
  u32* X2b = Y0;
  int* esrc = (int*)p;    p += (size_t)EE * 4;
  int* rp   = (int*)p;    p += ((size_t)(NN + 1) * 4 + 127) & ~(size_t)127;
  float* ds = (float*)p;  p += (size_t)NN * 4;
  char* zbeg = p;
  int* deg  = (int*)p;    p += (size_t)NN * 4;
  int* cnt  = (int*)p;    p += (size_t)NN * 4;
  float* gsum = (float*)p; p += 512;
  float* gsq  = (float*)p; p += 512;
  float* scale = (float*)p; p += 512;
  float* shift = (float*)p; p += 512;

  hipMemsetAsync(zbeg, 0, (size_t)NN * 8 + 1024, stream);  // deg, cnt, gsum, gsq

  k_deg<<<2048, 256, 0, stream>>>(dst, deg);
  k_dsqrt<<<(NN + 255) / 256, 256, 0, stream>>>(deg, ds);
  k_scan<<<1, 1024, 0, stream>>>(deg, rp);
  k_scatter<<<2048, 256, 0, stream>>>(src, dst, rp, cnt, esrc);
  k_prep<<<4096, 256, 0, stream>>>(feature, ds, X0b, Y0);
  k_prop1<<<NN / 4, 256, 0, stream>>>(Y0, ds, rp, esrc, X1b, Y1);
  k_prop2<<<NN / 4, 256, 0, stream>>>(Y1, X0b, ds, rp, esrc, X2b);
  k_gemm<<<(NN + 127) / 128, 256, 0, stream>>>(X0b, X1b, X2b, W, bias, snorm,
                                               out, gsum, gsq);
  k_bnprep<<<1, 128, 0, stream>>>(gsum, gsq, gamma, beta, scale, shift);
  k_apply<<<4096, 256, 0, stream>>>(out, scale, shift);
}

// Round 3
// 604.063 us; speedup vs baseline: 1.4657x; 1.1392x over previous
//
#include <hip/hip_runtime.h>

#define NN 100000
#define EE 1600000
#define DIM 128

typedef unsigned int u32;
typedef __attribute__((ext_vector_type(8))) short bf16x8;
typedef __attribute__((ext_vector_type(4))) float f32x4;

union U4 { uint4 u; bf16x8 h; };

__device__ __forceinline__ float lof(u32 u) { return __uint_as_float(u << 16); }
__device__ __forceinline__ float hif(u32 u) { return __uint_as_float(u & 0xffff0000u); }
__device__ __forceinline__ u32 pack_bf2(float a, float b) {
  u32 ua = __float_as_uint(a), ub = __float_as_uint(b);
  ua = (ua + 0x7fffu + ((ua >> 16) & 1u)) >> 16;
  ub = (ub + 0x7fffu + ((ub >> 16) & 1u)) & 0xffff0000u;
  return ua | ub;
}

// ---------------- degree ----------------
__global__ void k_deg(const int* __restrict__ dst, int* __restrict__ deg) {
  int i = blockIdx.x * blockDim.x + threadIdx.x;
  int st = gridDim.x * blockDim.x;
  for (int e = i; e < EE; e += st) atomicAdd(&deg[dst[e]], 1);
}

__global__ void k_dsqrt(const int* __restrict__ deg, float* __restrict__ ds) {
  int i = blockIdx.x * blockDim.x + threadIdx.x;
  if (i < NN) ds[i] = rsqrtf(fmaxf((float)deg[i], 1.0f));
}

// ---------------- single-block exclusive scan -> row_ptr ----------------
__global__ __launch_bounds__(1024) void k_scan(const int* __restrict__ deg,
                                               int* __restrict__ rp) {
  __shared__ int ps[1024];
  int t = threadIdx.x;
  const int chunk = (NN + 1023) / 1024;  // 98
  int beg = t * chunk;
  if (beg > NN) beg = NN;
  int end = beg + chunk;
  if (end > NN) end = NN;
  int s = 0;
  for (int i = beg; i < end; ++i) s += deg[i];
  ps[t] = s;
  __syncthreads();
  for (int off = 1; off < 1024; off <<= 1) {
    int v = (t >= off) ? ps[t - off] : 0;
    __syncthreads();
    ps[t] += v;
    __syncthreads();
  }
  int run = ps[t] - s;  // exclusive prefix
  for (int i = beg; i < end; ++i) { rp[i] = run; run += deg[i]; }
  if (end == NN) rp[NN] = run;
}

// ---------------- scatter edges into CSR order ----------------
__global__ void k_scatter(const int* __restrict__ src, const int* __restrict__ dst,
                          const int* __restrict__ rp, int* __restrict__ cnt,
                          int* __restrict__ esrc) {
  int i = blockIdx.x * blockDim.x + threadIdx.x;
  int st = gridDim.x * blockDim.x;
  for (int e = i; e < EE; e += st) {
    int d = dst[e];
    int pos = rp[d] + atomicAdd(&cnt[d], 1);
    esrc[pos] = src[e];
  }
}

// ---------------- prep: X0b = bf16(feature), Y0 = bf16(feature*ds) ----------------
__global__ void k_prep(const float* __restrict__ feature, const float* __restrict__ ds,
                       u32* __restrict__ X0b, u32* __restrict__ Y0) {
  const int total = NN * 32;  // uint2 count (4 dims each)
  int i = blockIdx.x * blockDim.x + threadIdx.x;
  int st = gridDim.x * blockDim.x;
  for (int j = i; j < total; j += st) {
    int n = j >> 5;
    float4 f = *(const float4*)(feature + (size_t)n * DIM + (j & 31) * 4);
    float dsn = ds[n];
    ((uint2*)X0b)[j] = make_uint2(pack_bf2(f.x, f.y), pack_bf2(f.z, f.w));
    ((uint2*)Y0)[j] = make_uint2(pack_bf2(f.x * dsn, f.y * dsn),
                                 pack_bf2(f.z * dsn, f.w * dsn));
  }
}

// ---------------- W transpose -> bf16: Wt[n][k], rows of 384 bf16 (192 u32) ----
__global__ void k_wprep(const float* __restrict__ W, u32* __restrict__ Wt) {
  int j = blockIdx.x * blockDim.x + threadIdx.x;
  if (j >= 128 * 192) return;
  int n = j / 192, ku = j - n * 192;
  int k = ku * 2;
  float w0 = W[(size_t)k * 128 + n];
  float w1 = W[(size_t)(k + 1) * 128 + n];
  Wt[j] = pack_bf2(w0, w1);
}

// ---------------- prop1: X1 = -ds[n]*sum Y0[s]; write X1b, Y1 = X1*ds[n] ----------------
__global__ __launch_bounds__(256) void k_prop1(const u32* __restrict__ Y0,
                                               const float* __restrict__ ds,
                                               const int* __restrict__ rp,
                                               const int* __restrict__ esrc,
                                               u32* __restrict__ X1b,
                                               u32* __restrict__ Y1) {
  int n = blockIdx.x * 4 + (threadIdx.x >> 6);
  int l = threadIdx.x & 63;
  int beg = rp[n], end = rp[n + 1];
  float a0x = 0, a0y = 0, a1x = 0, a1y = 0, a2x = 0, a2y = 0, a3x = 0, a3y = 0;
  int p = beg;
  for (; p + 4 <= end; p += 4) {
    int s0 = esrc[p], s1 = esrc[p + 1], s2 = esrc[p + 2], s3 = esrc[p + 3];
    u32 u0 = Y0[(size_t)s0 * 64 + l];
    u32 u1 = Y0[(size_t)s1 * 64 + l];
    u32 u2 = Y0[(size_t)s2 * 64 + l];
    u32 u3 = Y0[(size_t)s3 * 64 + l];
    a0x += lof(u0); a0y += hif(u0);
    a1x += lof(u1); a1y += hif(u1);
    a2x += lof(u2); a2y += hif(u2);
    a3x += lof(u3); a3y += hif(u3);
  }
  for (; p < end; ++p) {
    u32 u = Y0[(size_t)esrc[p] * 64 + l];
    a0x += lof(u); a0y += hif(u);
  }
  float dsn = ds[n];
  float x = -dsn * ((a0x + a1x) + (a2x + a3x));
  float y = -dsn * ((a0y + a1y) + (a2y + a3y));
  X1b[(size_t)n * 64 + l] = pack_bf2(x, y);
  Y1[(size_t)n * 64 + l] = pack_bf2(x * dsn, y * dsn);
}

// ---------------- prop2: X2 = -2*ds[n]*sum Y1[s] - X0 ----------------
__global__ __launch_bounds__(256) void k_prop2(const u32* __restrict__ Y1,
                                               const u32* __restrict__ X0b,
                                               const float* __restrict__ ds,
                                               const int* __restrict__ rp,
                                               const int* __restrict__ esrc,
                                               u32* __restrict__ X2b) {
  int n = blockIdx.x * 4 + (threadIdx.x >> 6);
  int l = threadIdx.x & 63;
  int beg = rp[n], end = rp[n + 1];
  float a0x = 0, a0y = 0, a1x = 0, a1y = 0, a2x = 0, a2y = 0, a3x = 0, a3y = 0;
  int p = beg;
  for (; p + 4 <= end; p += 4) {
    int s0 = esrc[p], s1 = esrc[p + 1], s2 = esrc[p + 2], s3 = esrc[p + 3];
    u32 u0 = Y1[(size_t)s0 * 64 + l];
    u32 u1 = Y1[(size_t)s1 * 64 + l];
    u32 u2 = Y1[(size_t)s2 * 64 + l];
    u32 u3 = Y1[(size_t)s3 * 64 + l];
    a0x += lof(u0); a0y += hif(u0);
    a1x += lof(u1); a1y += hif(u1);
    a2x += lof(u2); a2y += hif(u2);
    a3x += lof(u3); a3y += hif(u3);
  }
  for (; p < end; ++p) {
    u32 u = Y1[(size_t)esrc[p] * 64 + l];
    a0x += lof(u); a0y += hif(u);
  }
  float dsn = ds[n];
  u32 u0 = X0b[(size_t)n * 64 + l];
  float x = -2.0f * dsn * ((a0x + a1x) + (a2x + a3x)) - lof(u0);
  float y = -2.0f * dsn * ((a0y + a1y) + (a2y + a3y)) - hif(u0);
  X2b[(size_t)n * 64 + l] = pack_bf2(x, y);
}

// ---------------- MFMA GEMM: h = [X0|X1|X2] @ W + bias, h *= snorm; BN col sums ----
// per wave: 32 rows x 128 cols. a-frag: X rows direct from global (bf16).
// b-frag: Wt rows (= W columns) direct from global. Same k-slot convention both
// sides -> intra-K permutation cancels. D: col=lane&15, row=(lane>>4)*4+reg.
__device__ __forceinline__ void gemm_phase(const u32* __restrict__ A, size_t rA0,
                                           size_t rA1, const u32* __restrict__ wb,
                                           f32x4 (&acc)[2][8]) {
  #pragma unroll
  for (int ks = 0; ks < 4; ++ks) {
    U4 a0, a1;
    a0.u = *(const uint4*)(A + rA0 * 64 + ks * 16);
    a1.u = *(const uint4*)(A + rA1 * 64 + ks * 16);
    U4 b[8];
    #pragma unroll
    for (int nj = 0; nj < 8; ++nj)
      b[nj].u = *(const uint4*)(wb + (size_t)nj * 3072 + ks * 16);
    #pragma unroll
    for (int nj = 0; nj < 8; ++nj) {
      acc[0][nj] = __builtin_amdgcn_mfma_f32_16x16x32_bf16(a0.h, b[nj].h, acc[0][nj], 0, 0, 0);
      acc[1][nj] = __builtin_amdgcn_mfma_f32_16x16x32_bf16(a1.h, b[nj].h, acc[1][nj], 0, 0, 0);
    }
  }
}

__global__ __launch_bounds__(256) void k_gemm(const u32* __restrict__ X0b,
                                              const u32* __restrict__ X1b,
                                              const u32* __restrict__ X2b,
                                              const u32* __restrict__ Wt,
                                              const float* __restrict__ bias,
                                              const float* __restrict__ snorm,
                                              float* __restrict__ out,
                                              float* __restrict__ gsum,
                                              float* __restrict__ gsq) {
  __shared__ float ls[256];
  int tid = threadIdx.x;
  int wid = tid >> 6, lane = tid & 63;
  int l15 = lane & 15, g = lane >> 4;
  int row0 = (blockIdx.x * 4 + wid) * 32;
  bool active = (row0 + 32) <= NN;
  if (!active) row0 = 0;

  size_t rA0 = (size_t)(row0 + l15);
  size_t rA1 = (size_t)(row0 + 16 + l15);
  const u32* wb = Wt + (size_t)l15 * 192 + g * 4;  // + nj*3072 + kstep*16

  f32x4 acc[2][8];
  #pragma unroll
  for (int mi = 0; mi < 2; ++mi)
    #pragma unroll
    for (int nj = 0; nj < 8; ++nj) acc[mi][nj] = (f32x4){0.f, 0.f, 0.f, 0.f};

  gemm_phase(X0b + g * 4, rA0, rA1, wb, acc);
  gemm_phase(X1b + g * 4, rA0, rA1, wb + 64, acc);
  gemm_phase(X2b + g * 4, rA0, rA1, wb + 128, acc);

  float cs[8], cq[8];
  #pragma unroll
  for (int nj = 0; nj < 8; ++nj) { cs[nj] = 0.f; cq[nj] = 0.f; }
  if (active) {
    float bs[8];
    #pragma unroll
    for (int nj = 0; nj < 8; ++nj) bs[nj] = bias[nj * 16 + l15];
    #pragma unroll
    for (int mi = 0; mi < 2; ++mi) {
      #pragma unroll
      for (int r = 0; r < 4; ++r) {
        int row = row0 + mi * 16 + g * 4 + r;
        float sn = snorm[row];
        #pragma unroll
        for (int nj = 0; nj < 8; ++nj) {
          float h = (acc[mi][nj][r] + bs[nj]) * sn;
          out[(size_t)row * DIM + nj * 16 + l15] = h;
          cs[nj] += h;
          cq[nj] += h * h;
        }
      }
    }
  }
  ls[tid] = 0.f;
  __syncthreads();
  if (active) {
    #pragma unroll
    for (int nj = 0; nj < 8; ++nj) {
      atomicAdd(&ls[nj * 16 + l15], cs[nj]);
      atomicAdd(&ls[128 + nj * 16 + l15], cq[nj]);
    }
  }
  __syncthreads();
  if (tid < 128) {
    atomicAdd(&gsum[tid], ls[tid]);
    atomicAdd(&gsq[tid], ls[128 + tid]);
  }
}

// ---------------- BN prep + apply ----------------
__global__ void k_bnprep(const float* __restrict__ gsum, const float* __restrict__ gsq,
                         const float* __restrict__ gamma, const float* __restrict__ beta,
                         float* __restrict__ scale, float* __restrict__ shift) {
  int c = threadIdx.x;
  if (c < DIM) {
    float mean = gsum[c] * (1.0f / NN);
    float var = gsq[c] * (1.0f / NN) - mean * mean;
    var = fmaxf(var, 0.f);
    float sc = gamma[c] * rsqrtf(var + 1e-5f);
    scale[c] = sc;
    shift[c] = beta[c] - mean * sc;
  }
}

__global__ void k_apply(float* __restrict__ out, const float* __restrict__ scale,
                        const float* __restrict__ shift) {
  const int total4 = NN * DIM / 4;
  int i = blockIdx.x * blockDim.x + threadIdx.x;
  int st = gridDim.x * blockDim.x;
  for (int i4 = i; i4 < total4; i4 += st) {
    int c4 = (i4 & 31) * 4;
    float4 v = ((float4*)out)[i4];
    float4 s = *(const float4*)(scale + c4);
    float4 sh = *(const float4*)(shift + c4);
    v.x = fmaxf(fmaf(v.x, s.x, sh.x), 0.f);
    v.y = fmaxf(fmaf(v.y, s.y, sh.y), 0.f);
    v.z = fmaxf(fmaf(v.z, s.z, sh.z), 0.f);
    v.w = fmaxf(fmaf(v.w, s.w, sh.w), 0.f);
    ((float4*)out)[i4] = v;
  }
}

extern "C" void kernel_launch(void* const* d_in, const int* in_sizes, int n_in,
                              void* d_out, int out_size, void* d_ws, size_t ws_size,
                              hipStream_t stream) {
  const float* feature = (const float*)d_in[0];
  const float* snorm   = (const float*)d_in[1];
  const int*   src     = (const int*)d_in[2];
  const int*   dst     = (const int*)d_in[3];
  const float* W       = (const float*)d_in[4];
  const float* bias    = (const float*)d_in[5];
  const float* gamma   = (const float*)d_in[6];
  const float* beta    = (const float*)d_in[7];
  float* out = (float*)d_out;

  const size_t TBL = (size_t)NN * 64 * sizeof(u32);  // 25.6 MB
  char* p = (char*)d_ws;
  u32* X0b = (u32*)p; p += TBL;
  u32* Y0  = (u32*)p; p += TBL;   // reused as X2b after prop1 consumes it
  u32* X1b = (u32*)p; p += TBL;
  u32* Y1  = (u32*)p; p += TBL;
  u32* X2b = Y0;
  u32* Wt  = (u32*)p; p += 128 * 192 * sizeof(u32);  // 98.3 KB
  int* esrc = (int*)p;    p += (size_t)EE * 4;
  int* rp   = (int*)p;    p += ((size_t)(NN + 1) * 4 + 127) & ~(size_t)127;
  float* ds = (float*)p;  p += (size_t)NN * 4;
  char* zbeg = p;
  int* deg  = (int*)p;    p += (size_t)NN * 4;
  int* cnt  = (int*)p;    p += (size_t)NN * 4;
  float* gsum = (float*)p; p += 512;
  float* gsq  = (float*)p; p += 512;
  float* scale = (float*)p; p += 512;
  float* shift = (float*)p; p += 512;

  hipMemsetAsync(zbeg, 0, (size_t)NN * 8 + 1024, stream);  // deg, cnt, gsum, gsq

  k_deg<<<2048, 256, 0, stream>>>(dst, deg);
  k_dsqrt<<<(NN + 255) / 256, 256, 0, stream>>>(deg, ds);
  k_scan<<<1, 1024, 0, stream>>>(deg, rp);
  k_scatter<<<2048, 256, 0, stream>>>(src, dst, rp, cnt, esrc);
  k_prep<<<4096, 256, 0, stream>>>(feature, ds, X0b, Y0);
  k_wprep<<<96, 256, 0, stream>>>(W, Wt);
  k_prop1<<<NN / 4, 256, 0, stream>>>(Y0, ds, rp, esrc, X1b, Y1);
  k_prop2<<<NN / 4, 256, 0, stream>>>(Y1, X0b, ds, rp, esrc, X2b);
  {
    int nwaves = NN / 32;  // 3125
    int nblk = (nwaves + 3) / 4;  // 782
    k_gemm<<<nblk, 256, 0, stream>>>(X0b, X1b, X2b, Wt, bias, snorm, out, gsum, gsq);
  }
  k_bnprep<<<1, 128, 0, stream>>>(gsum, gsq, gamma, beta, scale, shift);
  k_apply<<<4096, 256, 0, stream>>>(out, scale, shift);
}

// Round 4
// 460.622 us; speedup vs baseline: 1.9222x; 1.3114x over previous
//
#include <hip/hip_runtime.h>

#define NN 100000
#define EE 1600000
#define DIM 128
#define NB ((NN + 255) / 256)  // 391

typedef unsigned int u32;
typedef __attribute__((ext_vector_type(8))) short bf16x8;
typedef __attribute__((ext_vector_type(4))) float f32x4;

union U4 { uint4 u; bf16x8 h; };

__device__ __forceinline__ float lof(u32 u) { return __uint_as_float(u << 16); }
__device__ __forceinline__ float hif(u32 u) { return __uint_as_float(u & 0xffff0000u); }
__device__ __forceinline__ u32 pack_bf2(float a, float b) {
  u32 ua = __float_as_uint(a), ub = __float_as_uint(b);
  ua = (ua + 0x7fffu + ((ua >> 16) & 1u)) >> 16;
  ub = (ub + 0x7fffu + ((ub >> 16) & 1u)) & 0xffff0000u;
  return ua | ub;
}

// ---------------- degree ----------------
__global__ void k_deg(const int* __restrict__ dst, int* __restrict__ deg) {
  int i = blockIdx.x * blockDim.x + threadIdx.x;
  int st = gridDim.x * blockDim.x;
  for (int e = i; e < EE; e += st) atomicAdd(&deg[dst[e]], 1);
}

// ---------------- two-level scan: block sums ----------------
__global__ __launch_bounds__(256) void k_bsum(const int* __restrict__ deg,
                                              int* __restrict__ bsum) {
  __shared__ int ps[256];
  int t = threadIdx.x;
  int i = blockIdx.x * 256 + t;
  int v = (i < NN) ? deg[i] : 0;
  ps[t] = v;
  __syncthreads();
  #pragma unroll
  for (int off = 128; off > 0; off >>= 1) {
    if (t < off) ps[t] += ps[t + off];
    __syncthreads();
  }
  if (t == 0) bsum[blockIdx.x] = ps[0];
}

// ---------------- scan the 391 block sums (1 small block) ----------------
__global__ __launch_bounds__(512) void k_bscan(const int* __restrict__ bsum,
                                               int* __restrict__ bpre,
                                               int* __restrict__ rp) {
  __shared__ int ps[512];
  int t = threadIdx.x;
  int v = (t < NB) ? bsum[t] : 0;
  ps[t] = v;
  __syncthreads();
  #pragma unroll
  for (int off = 1; off < 512; off <<= 1) {
    int u = (t >= off) ? ps[t - off] : 0;
    __syncthreads();
    ps[t] += u;
    __syncthreads();
  }
  if (t < NB) bpre[t] = ps[t] - v;  // exclusive
  if (t == 0) rp[NN] = EE;
}

// ---------------- fill rp + fused ds = rsqrt(max(deg,1)) ----------------
__global__ __launch_bounds__(256) void k_rpfill(const int* __restrict__ deg,
                                                const int* __restrict__ bpre,
                                                int* __restrict__ rp,
                                                float* __restrict__ ds) {
  __shared__ int ps[256];
  int t = threadIdx.x;
  int i = blockIdx.x * 256 + t;
  int v = (i < NN) ? deg[i] : 0;
  ps[t] = v;
  __syncthreads();
  #pragma unroll
  for (int off = 1; off < 256; off <<= 1) {
    int u = (t >= off) ? ps[t - off] : 0;
    __syncthreads();
    ps[t] += u;
    __syncthreads();
  }
  if (i < NN) {
    rp[i] = bpre[blockIdx.x] + ps[t] - v;
    ds[i] = rsqrtf(fmaxf((float)v, 1.0f));
  }
}

// ---------------- scatter edges into CSR order ----------------
__global__ void k_scatter(const int* __restrict__ src, const int* __restrict__ dst,
                          const int* __restrict__ rp, int* __restrict__ cnt,
                          int* __restrict__ esrc) {
  int i = blockIdx.x * blockDim.x + threadIdx.x;
  int st = gridDim.x * blockDim.x;
  for (int e = i; e < EE; e += st) {
    int d = dst[e];
    int pos = rp[d] + atomicAdd(&cnt[d], 1);
    esrc[pos] = src[e];
  }
}

// ---------------- prep: X0b = bf16(feature), Y0 = bf16(feature*ds) ----------------
__global__ void k_prep(const float* __restrict__ feature, const float* __restrict__ ds,
                       u32* __restrict__ X0b, u32* __restrict__ Y0) {
  const int total = NN * 32;  // uint2 count (4 dims each)
  int i = blockIdx.x * blockDim.x + threadIdx.x;
  int st = gridDim.x * blockDim.x;
  for (int j = i; j < total; j += st) {
    int n = j >> 5;
    float4 f = *(const float4*)(feature + (size_t)n * DIM + (j & 31) * 4);
    float dsn = ds[n];
    ((uint2*)X0b)[j] = make_uint2(pack_bf2(f.x, f.y), pack_bf2(f.z, f.w));
    ((uint2*)Y0)[j] = make_uint2(pack_bf2(f.x * dsn, f.y * dsn),
                                 pack_bf2(f.z * dsn, f.w * dsn));
  }
}

// ---------------- W transpose -> bf16: Wt[n][k], rows of 384 bf16 (192 u32) ----
__global__ void k_wprep(const float* __restrict__ W, u32* __restrict__ Wt) {
  int j = blockIdx.x * blockDim.x + threadIdx.x;
  if (j >= 128 * 192) return;
  int n = j / 192, ku = j - n * 192;
  int k = ku * 2;
  float w0 = W[(size_t)k * 128 + n];
  float w1 = W[(size_t)(k + 1) * 128 + n];
  Wt[j] = pack_bf2(w0, w1);
}

// ---------------- prop1: X1 = -ds[n]*sum Y0[s]; write X1b, Y1 = X1*ds[n] ----------------
__global__ __launch_bounds__(256) void k_prop1(const u32* __restrict__ Y0,
                                               const float* __restrict__ ds,
                                               const int* __restrict__ rp,
                                               const int* __restrict__ esrc,
                                               u32* __restrict__ X1b,
                                               u32* __restrict__ Y1) {
  int n = blockIdx.x * 4 + (threadIdx.x >> 6);
  int l = threadIdx.x & 63;
  int beg = rp[n], end = rp[n + 1];
  float a0x = 0, a0y = 0, a1x = 0, a1y = 0, a2x = 0, a2y = 0, a3x = 0, a3y = 0;
  int p = beg;
  for (; p + 4 <= end; p += 4) {
    int s0 = esrc[p], s1 = esrc[p + 1], s2 = esrc[p + 2], s3 = esrc[p + 3];
    u32 u0 = Y0[(size_t)s0 * 64 + l];
    u32 u1 = Y0[(size_t)s1 * 64 + l];
    u32 u2 = Y0[(size_t)s2 * 64 + l];
    u32 u3 = Y0[(size_t)s3 * 64 + l];
    a0x += lof(u0); a0y += hif(u0);
    a1x += lof(u1); a1y += hif(u1);
    a2x += lof(u2); a2y += hif(u2);
    a3x += lof(u3); a3y += hif(u3);
  }
  for (; p < end; ++p) {
    u32 u = Y0[(size_t)esrc[p] * 64 + l];
    a0x += lof(u); a0y += hif(u);
  }
  float dsn = ds[n];
  float x = -dsn * ((a0x + a1x) + (a2x + a3x));
  float y = -dsn * ((a0y + a1y) + (a2y + a3y));
  X1b[(size_t)n * 64 + l] = pack_bf2(x, y);
  Y1[(size_t)n * 64 + l] = pack_bf2(x * dsn, y * dsn);
}

// ---------------- prop2: X2 = -2*ds[n]*sum Y1[s] - X0 ----------------
__global__ __launch_bounds__(256) void k_prop2(const u32* __restrict__ Y1,
                                               const u32* __restrict__ X0b,
                                               const float* __restrict__ ds,
                                               const int* __restrict__ rp,
                                               const int* __restrict__ esrc,
                                               u32* __restrict__ X2b) {
  int n = blockIdx.x * 4 + (threadIdx.x >> 6);
  int l = threadIdx.x & 63;
  int beg = rp[n], end = rp[n + 1];
  float a0x = 0, a0y = 0, a1x = 0, a1y = 0, a2x = 0, a2y = 0, a3x = 0, a3y = 0;
  int p = beg;
  for (; p + 4 <= end; p += 4) {
    int s0 = esrc[p], s1 = esrc[p + 1], s2 = esrc[p + 2], s3 = esrc[p + 3];
    u32 u0 = Y1[(size_t)s0 * 64 + l];
    u32 u1 = Y1[(size_t)s1 * 64 + l];
    u32 u2 = Y1[(size_t)s2 * 64 + l];
    u32 u3 = Y1[(size_t)s3 * 64 + l];
    a0x += lof(u0); a0y += hif(u0);
    a1x += lof(u1); a1y += hif(u1);
    a2x += lof(u2); a2y += hif(u2);
    a3x += lof(u3); a3y += hif(u3);
  }
  for (; p < end; ++p) {
    u32 u = Y1[(size_t)esrc[p] * 64 + l];
    a0x += lof(u); a0y += hif(u);
  }
  float dsn = ds[n];
  u32 u0 = X0b[(size_t)n * 64 + l];
  float x = -2.0f * dsn * ((a0x + a1x) + (a2x + a3x)) - lof(u0);
  float y = -2.0f * dsn * ((a0y + a1y) + (a2y + a3y)) - hif(u0);
  X2b[(size_t)n * 64 + l] = pack_bf2(x, y);
}

// ---------------- MFMA GEMM: h = [X0|X1|X2] @ W + bias, h *= snorm; BN col sums ----
__device__ __forceinline__ void gemm_phase(const u32* __restrict__ A, size_t rA0,
                                           size_t rA1, const u32* __restrict__ wb,
                                           f32x4 (&acc)[2][8]) {
  #pragma unroll
  for (int ks = 0; ks < 4; ++ks) {
    U4 a0, a1;
    a0.u = *(const uint4*)(A + rA0 * 64 + ks * 16);
    a1.u = *(const uint4*)(A + rA1 * 64 + ks * 16);
    U4 b[8];
    #pragma unroll
    for (int nj = 0; nj < 8; ++nj)
      b[nj].u = *(const uint4*)(wb + (size_t)nj * 3072 + ks * 16);
    #pragma unroll
    for (int nj = 0; nj < 8; ++nj) {
      acc[0][nj] = __builtin_amdgcn_mfma_f32_16x16x32_bf16(a0.h, b[nj].h, acc[0][nj], 0, 0, 0);
      acc[1][nj] = __builtin_amdgcn_mfma_f32_16x16x32_bf16(a1.h, b[nj].h, acc[1][nj], 0, 0, 0);
    }
  }
}

__global__ __launch_bounds__(256) void k_gemm(const u32* __restrict__ X0b,
                                              const u32* __restrict__ X1b,
                                              const u32* __restrict__ X2b,
                                              const u32* __restrict__ Wt,
                                              const float* __restrict__ bias,
                                              const float* __restrict__ snorm,
                                              float* __restrict__ out,
                                              float* __restrict__ gsum,
                                              float* __restrict__ gsq) {
  __shared__ float ls[256];
  int tid = threadIdx.x;
  int wid = tid >> 6, lane = tid & 63;
  int l15 = lane & 15, g = lane >> 4;
  int row0 = (blockIdx.x * 4 + wid) * 32;
  bool active = (row0 + 32) <= NN;
  if (!active) row0 = 0;

  size_t rA0 = (size_t)(row0 + l15);
  size_t rA1 = (size_t)(row0 + 16 + l15);
  const u32* wb = Wt + (size_t)l15 * 192 + g * 4;

  f32x4 acc[2][8];
  #pragma unroll
  for (int mi = 0; mi < 2; ++mi)
    #pragma unroll
    for (int nj = 0; nj < 8; ++nj) acc[mi][nj] = (f32x4){0.f, 0.f, 0.f, 0.f};

  gemm_phase(X0b + g * 4, rA0, rA1, wb, acc);
  gemm_phase(X1b + g * 4, rA0, rA1, wb + 64, acc);
  gemm_phase(X2b + g * 4, rA0, rA1, wb + 128, acc);

  float cs[8], cq[8];
  #pragma unroll
  for (int nj = 0; nj < 8; ++nj) { cs[nj] = 0.f; cq[nj] = 0.f; }
  if (active) {
    float bs[8];
    #pragma unroll
    for (int nj = 0; nj < 8; ++nj) bs[nj] = bias[nj * 16 + l15];
    #pragma unroll
    for (int mi = 0; mi < 2; ++mi) {
      #pragma unroll
      for (int r = 0; r < 4; ++r) {
        int row = row0 + mi * 16 + g * 4 + r;
        float sn = snorm[row];
        #pragma unroll
        for (int nj = 0; nj < 8; ++nj) {
          float h = (acc[mi][nj][r] + bs[nj]) * sn;
          out[(size_t)row * DIM + nj * 16 + l15] = h;
          cs[nj] += h;
          cq[nj] += h * h;
        }
      }
    }
  }
  ls[tid] = 0.f;
  __syncthreads();
  if (active) {
    #pragma unroll
    for (int nj = 0; nj < 8; ++nj) {
      atomicAdd(&ls[nj * 16 + l15], cs[nj]);
      atomicAdd(&ls[128 + nj * 16 + l15], cq[nj]);
    }
  }
  __syncthreads();
  if (tid < 128) {
    atomicAdd(&gsum[tid], ls[tid]);
    atomicAdd(&gsq[tid], ls[128 + tid]);
  }
}

// ---------------- BN prep + apply ----------------
__global__ void k_bnprep(const float* __restrict__ gsum, const float* __restrict__ gsq,
                         const float* __restrict__ gamma, const float* __restrict__ beta,
                         float* __restrict__ scale, float* __restrict__ shift) {
  int c = threadIdx.x;
  if (c < DIM) {
    float mean = gsum[c] * (1.0f / NN);
    float var = gsq[c] * (1.0f / NN) - mean * mean;
    var = fmaxf(var, 0.f);
    float sc = gamma[c] * rsqrtf(var + 1e-5f);
    scale[c] = sc;
    shift[c] = beta[c] - mean * sc;
  }
}

__global__ void k_apply(float* __restrict__ out, const float* __restrict__ scale,
                        const float* __restrict__ shift) {
  const int total4 = NN * DIM / 4;
  int i = blockIdx.x * blockDim.x + threadIdx.x;
  int st = gridDim.x * blockDim.x;
  for (int i4 = i; i4 < total4; i4 += st) {
    int c4 = (i4 & 31) * 4;
    float4 v = ((float4*)out)[i4];
    float4 s = *(const float4*)(scale + c4);
    float4 sh = *(const float4*)(shift + c4);
    v.x = fmaxf(fmaf(v.x, s.x, sh.x), 0.f);
    v.y = fmaxf(fmaf(v.y, s.y, sh.y), 0.f);
    v.z = fmaxf(fmaf(v.z, s.z, sh.z), 0.f);
    v.w = fmaxf(fmaf(v.w, s.w, sh.w), 0.f);
    ((float4*)out)[i4] = v;
  }
}

extern "C" void kernel_launch(void* const* d_in, const int* in_sizes, int n_in,
                              void* d_out, int out_size, void* d_ws, size_t ws_size,
                              hipStream_t stream) {
  const float* feature = (const float*)d_in[0];
  const float* snorm   = (const float*)d_in[1];
  const int*   src     = (const int*)d_in[2];
  const int*   dst     = (const int*)d_in[3];
  const float* W       = (const float*)d_in[4];
  const float* bias    = (const float*)d_in[5];
  const float* gamma   = (const float*)d_in[6];
  const float* beta    = (const float*)d_in[7];
  float* out = (float*)d_out;

  const size_t TBL = (size_t)NN * 64 * sizeof(u32);  // 25.6 MB
  char* p = (char*)d_ws;
  u32* X0b = (u32*)p; p += TBL;
  u32* Y0  = (u32*)p; p += TBL;   // reused as X2b after prop1 consumes it
  u32* X1b = (u32*)p; p += TBL;
  u32* Y1  = (u32*)p; p += TBL;
  u32* X2b = Y0;
  u32* Wt  = (u32*)p; p += 128 * 192 * sizeof(u32);  // 98.3 KB
  int* esrc = (int*)p;    p += (size_t)EE * 4;
  int* rp   = (int*)p;    p += ((size_t)(NN + 1) * 4 + 127) & ~(size_t)127;
  float* ds = (float*)p;  p += (size_t)NN * 4;
  int* bsum = (int*)p;    p += 512 * 4;
  int* bpre = (int*)p;    p += 512 * 4;
  char* zbeg = p;
  int* deg  = (int*)p;    p += (size_t)NN * 4;
  int* cnt  = (int*)p;    p += (size_t)NN * 4;
  float* gsum = (float*)p; p += 512;
  float* gsq  = (float*)p; p += 512;
  float* scale = (float*)p; p += 512;
  float* shift = (float*)p; p += 512;

  hipMemsetAsync(zbeg, 0, (size_t)NN * 8 + 1024, stream);  // deg, cnt, gsum, gsq

  k_deg<<<2048, 256, 0, stream>>>(dst, deg);
  k_bsum<<<NB, 256, 0, stream>>>(deg, bsum);
  k_bscan<<<1, 512, 0, stream>>>(bsum, bpre, rp);
  k_rpfill<<<NB, 256, 0, stream>>>(deg, bpre, rp, ds);
  k_scatter<<<2048, 256, 0, stream>>>(src, dst, rp, cnt, esrc);
  k_prep<<<4096, 256, 0, stream>>>(feature, ds, X0b, Y0);
  k_wprep<<<96, 256, 0, stream>>>(W, Wt);
  k_prop1<<<NN / 4, 256, 0, stream>>>(Y0, ds, rp, esrc, X1b, Y1);
  k_prop2<<<NN / 4, 256, 0, stream>>>(Y1, X0b, ds, rp, esrc, X2b);
  {
    int nwaves = NN / 32;  // 3125
    int nblk = (nwaves + 3) / 4;  // 782
    k_gemm<<<nblk, 256, 0, stream>>>(X0b, X1b, X2b, Wt, bias, snorm, out, gsum, gsq);
  }
  k_bnprep<<<1, 128, 0, stream>>>(gsum, gsq, gamma, beta, scale, shift);
  k_apply<<<4096, 256, 0, stream>>>(out, scale, shift);
}

// Round 5
// 338.544 us; speedup vs baseline: 2.6153x; 1.3606x over previous
//
#include <hip/hip_runtime.h>

#define NN 100000
#define EE 1600000
#define DIM 128
#define NBUCK ((NN + 255) >> 8)   // 391 buckets of 256 nodes
#define B1 128                    // bucket-pass blocks
#define CH ((EE + B1 - 1) / B1)   // 12500 edges per block

typedef unsigned int u32;
typedef __attribute__((ext_vector_type(8))) short bf16x8;
typedef __attribute__((ext_vector_type(4))) float f32x4;

union U4 { uint4 u; bf16x8 h; };

__device__ __forceinline__ float lof(u32 u) { return __uint_as_float(u << 16); }
__device__ __forceinline__ float hif(u32 u) { return __uint_as_float(u & 0xffff0000u); }
__device__ __forceinline__ u32 pack_bf2(float a, float b) {
  u32 ua = __float_as_uint(a), ub = __float_as_uint(b);
  ua = (ua + 0x7fffu + ((ua >> 16) & 1u)) >> 16;
  ub = (ub + 0x7fffu + ((ub >> 16) & 1u)) & 0xffff0000u;
  return ua | ub;
}

// ---------------- pass A: per-block bucket histogram ----------------
__global__ __launch_bounds__(256) void k_hist(const int* __restrict__ dst,
                                              int* __restrict__ hist_t) {
  __shared__ int h[NBUCK];
  for (int i = threadIdx.x; i < NBUCK; i += 256) h[i] = 0;
  __syncthreads();
  int e0 = blockIdx.x * CH;
  int e1 = e0 + CH < EE ? e0 + CH : EE;
  for (int e = e0 + threadIdx.x; e < e1; e += 256)
    atomicAdd(&h[dst[e] >> 8], 1);
  __syncthreads();
  for (int i = threadIdx.x; i < NBUCK; i += 256)
    hist_t[i * B1 + blockIdx.x] = h[i];
}

// ---------------- pass B: per-bucket scan over blocks ----------------
__global__ __launch_bounds__(B1) void k_boff(const int* __restrict__ hist_t,
                                             int* __restrict__ blockoff,
                                             int* __restrict__ btot) {
  __shared__ int ps[B1];
  int j = blockIdx.x, t = threadIdx.x;
  int v = hist_t[j * B1 + t];
  ps[t] = v;
  __syncthreads();
  #pragma unroll
  for (int off = 1; off < B1; off <<= 1) {
    int u = (t >= off) ? ps[t - off] : 0;
    __syncthreads();
    ps[t] += u;
    __syncthreads();
  }
  blockoff[j * B1 + t] = ps[t] - v;
  if (t == B1 - 1) btot[j] = ps[t];
}

// ---------------- pass B2: scan bucket totals -> bbase ----------------
__global__ __launch_bounds__(512) void k_bbase(const int* __restrict__ btot,
                                               int* __restrict__ bbase) {
  __shared__ int ps[512];
  int t = threadIdx.x;
  int v = (t < NBUCK) ? btot[t] : 0;
  ps[t] = v;
  __syncthreads();
  #pragma unroll
  for (int off = 1; off < 512; off <<= 1) {
    int u = (t >= off) ? ps[t - off] : 0;
    __syncthreads();
    ps[t] += u;
    __syncthreads();
  }
  if (t < NBUCK) bbase[t] = ps[t] - v;
  if (t == 0) bbase[NBUCK] = EE;
}

// ---------------- pass C: scatter (dst,src) pairs into bucket regions ----------------
__global__ __launch_bounds__(256) void k_bucket(const int* __restrict__ src,
                                                const int* __restrict__ dst,
                                                const int* __restrict__ bbase,
                                                const int* __restrict__ blockoff,
                                                int2* __restrict__ epair) {
  __shared__ int cnt[NBUCK];
  for (int i = threadIdx.x; i < NBUCK; i += 256) cnt[i] = 0;
  __syncthreads();
  int e0 = blockIdx.x * CH;
  int e1 = e0 + CH < EE ? e0 + CH : EE;
  for (int e = e0 + threadIdx.x; e < e1; e += 256) {
    int d = dst[e], s = src[e];
    int j = d >> 8;
    int loc = atomicAdd(&cnt[j], 1);
    epair[bbase[j] + blockoff[j * B1 + blockIdx.x] + loc] = make_int2(d, s);
  }
}

// ---------------- pass D: per-bucket deg/ds/rp + fine scatter -> esrc ----------------
__global__ __launch_bounds__(256) void k_fine(const int2* __restrict__ epair,
                                              const int* __restrict__ bbase,
                                              int* __restrict__ rp,
                                              float* __restrict__ ds,
                                              int* __restrict__ esrc) {
  __shared__ int cntA[256], cntB[256], rpl[256], ps[256];
  int j = blockIdx.x, t = threadIdx.x;
  int node0 = j << 8;
  int e0 = bbase[j], e1 = bbase[j + 1];
  cntA[t] = 0;
  cntB[t] = 0;
  __syncthreads();
  for (int e = e0 + t; e < e1; e += 256)
    atomicAdd(&cntA[epair[e].x & 255], 1);
  __syncthreads();
  int deg = cntA[t];
  ps[t] = deg;
  __syncthreads();
  #pragma unroll
  for (int off = 1; off < 256; off <<= 1) {
    int u = (t >= off) ? ps[t - off] : 0;
    __syncthreads();
    ps[t] += u;
    __syncthreads();
  }
  rpl[t] = e0 + ps[t] - deg;
  __syncthreads();
  int node = node0 + t;
  if (node < NN) {
    rp[node] = rpl[t];
    ds[node] = rsqrtf(fmaxf((float)deg, 1.0f));
  }
  if (j == 0 && t == 0) rp[NN] = EE;
  for (int e = e0 + t; e < e1; e += 256) {
    int2 pr = epair[e];
    int d = pr.x & 255;
    int pos = rpl[d] + atomicAdd(&cntB[d], 1);
    esrc[pos] = pr.y;
  }
}

// ---------------- prep: X0b = bf16(feature), Y0 = bf16(feature*ds) ----------------
__global__ void k_prep(const float* __restrict__ feature, const float* __restrict__ ds,
                       u32* __restrict__ X0b, u32* __restrict__ Y0) {
  const int total = NN * 32;  // uint2 count (4 dims each)
  int i = blockIdx.x * blockDim.x + threadIdx.x;
  int st = gridDim.x * blockDim.x;
  for (int j = i; j < total; j += st) {
    int n = j >> 5;
    float4 f = *(const float4*)(feature + (size_t)n * DIM + (j & 31) * 4);
    float dsn = ds[n];
    ((uint2*)X0b)[j] = make_uint2(pack_bf2(f.x, f.y), pack_bf2(f.z, f.w));
    ((uint2*)Y0)[j] = make_uint2(pack_bf2(f.x * dsn, f.y * dsn),
                                 pack_bf2(f.z * dsn, f.w * dsn));
  }
}

// ---------------- W transpose -> bf16: Wt[n][k], rows of 384 bf16 (192 u32) ----
__global__ void k_wprep(const float* __restrict__ W, u32* __restrict__ Wt) {
  int j = blockIdx.x * blockDim.x + threadIdx.x;
  if (j >= 128 * 192) return;
  int n = j / 192, ku = j - n * 192;
  int k = ku * 2;
  float w0 = W[(size_t)k * 128 + n];
  float w1 = W[(size_t)(k + 1) * 128 + n];
  Wt[j] = pack_bf2(w0, w1);
}

// ---------------- prop1: X1 = -ds[n]*sum Y0[s]; write X1b, Y1 = X1*ds[n] ----------------
__global__ __launch_bounds__(256) void k_prop1(const u32* __restrict__ Y0,
                                               const float* __restrict__ ds,
                                               const int* __restrict__ rp,
                                               const int* __restrict__ esrc,
                                               u32* __restrict__ X1b,
                                               u32* __restrict__ Y1) {
  int n = blockIdx.x * 4 + (threadIdx.x >> 6);
  int l = threadIdx.x & 63;
  int beg = rp[n], end = rp[n + 1];
  float a0x = 0, a0y = 0, a1x = 0, a1y = 0, a2x = 0, a2y = 0, a3x = 0, a3y = 0;
  int p = beg;
  for (; p + 4 <= end; p += 4) {
    int s0 = esrc[p], s1 = esrc[p + 1], s2 = esrc[p + 2], s3 = esrc[p + 3];
    u32 u0 = Y0[(size_t)s0 * 64 + l];
    u32 u1 = Y0[(size_t)s1 * 64 + l];
    u32 u2 = Y0[(size_t)s2 * 64 + l];
    u32 u3 = Y0[(size_t)s3 * 64 + l];
    a0x += lof(u0); a0y += hif(u0);
    a1x += lof(u1); a1y += hif(u1);
    a2x += lof(u2); a2y += hif(u2);
    a3x += lof(u3); a3y += hif(u3);
  }
  for (; p < end; ++p) {
    u32 u = Y0[(size_t)esrc[p] * 64 + l];
    a0x += lof(u); a0y += hif(u);
  }
  float dsn = ds[n];
  float x = -dsn * ((a0x + a1x) + (a2x + a3x));
  float y = -dsn * ((a0y + a1y) + (a2y + a3y));
  X1b[(size_t)n * 64 + l] = pack_bf2(x, y);
  Y1[(size_t)n * 64 + l] = pack_bf2(x * dsn, y * dsn);
}

// ---------------- prop2: X2 = -2*ds[n]*sum Y1[s] - X0 ----------------
__global__ __launch_bounds__(256) void k_prop2(const u32* __restrict__ Y1,
                                               const u32* __restrict__ X0b,
                                               const float* __restrict__ ds,
                                               const int* __restrict__ rp,
                                               const int* __restrict__ esrc,
                                               u32* __restrict__ X2b) {
  int n = blockIdx.x * 4 + (threadIdx.x >> 6);
  int l = threadIdx.x & 63;
  int beg = rp[n], end = rp[n + 1];
  float a0x = 0, a0y = 0, a1x = 0, a1y = 0, a2x = 0, a2y = 0, a3x = 0, a3y = 0;
  int p = beg;
  for (; p + 4 <= end; p += 4) {
    int s0 = esrc[p], s1 = esrc[p + 1], s2 = esrc[p + 2], s3 = esrc[p + 3];
    u32 u0 = Y1[(size_t)s0 * 64 + l];
    u32 u1 = Y1[(size_t)s1 * 64 + l];
    u32 u2 = Y1[(size_t)s2 * 64 + l];
    u32 u3 = Y1[(size_t)s3 * 64 + l];
    a0x += lof(u0); a0y += hif(u0);
    a1x += lof(u1); a1y += hif(u1);
    a2x += lof(u2); a2y += hif(u2);
    a3x += lof(u3); a3y += hif(u3);
  }
  for (; p < end; ++p) {
    u32 u = Y1[(size_t)esrc[p] * 64 + l];
    a0x += lof(u); a0y += hif(u);
  }
  float dsn = ds[n];
  u32 u0 = X0b[(size_t)n * 64 + l];
  float x = -2.0f * dsn * ((a0x + a1x) + (a2x + a3x)) - lof(u0);
  float y = -2.0f * dsn * ((a0y + a1y) + (a2y + a3y)) - hif(u0);
  X2b[(size_t)n * 64 + l] = pack_bf2(x, y);
}

// ---------------- MFMA GEMM: h = [X0|X1|X2] @ W + bias, h *= snorm; BN col sums ----
__device__ __forceinline__ void gemm_phase(const u32* __restrict__ A, size_t rA0,
                                           size_t rA1, const u32* __restrict__ wb,
                                           f32x4 (&acc)[2][8]) {
  #pragma unroll
  for (int ks = 0; ks < 4; ++ks) {
    U4 a0, a1;
    a0.u = *(const uint4*)(A + rA0 * 64 + ks * 16);
    a1.u = *(const uint4*)(A + rA1 * 64 + ks * 16);
    U4 b[8];
    #pragma unroll
    for (int nj = 0; nj < 8; ++nj)
      b[nj].u = *(const uint4*)(wb + (size_t)nj * 3072 + ks * 16);
    #pragma unroll
    for (int nj = 0; nj < 8; ++nj) {
      acc[0][nj] = __builtin_amdgcn_mfma_f32_16x16x32_bf16(a0.h, b[nj].h, acc[0][nj], 0, 0, 0);
      acc[1][nj] = __builtin_amdgcn_mfma_f32_16x16x32_bf16(a1.h, b[nj].h, acc[1][nj], 0, 0, 0);
    }
  }
}

__global__ __launch_bounds__(256) void k_gemm(const u32* __restrict__ X0b,
                                              const u32* __restrict__ X1b,
                                              const u32* __restrict__ X2b,
                                              const u32* __restrict__ Wt,
                                              const float* __restrict__ bias,
                                              const float* __restrict__ snorm,
                                              float* __restrict__ out,
                                              float* __restrict__ gsum,
                                              float* __restrict__ gsq) {
  __shared__ float ls[256];
  int tid = threadIdx.x;
  int wid = tid >> 6, lane = tid & 63;
  int l15 = lane & 15, g = lane >> 4;
  int row0 = (blockIdx.x * 4 + wid) * 32;
  bool active = (row0 + 32) <= NN;
  if (!active) row0 = 0;

  size_t rA0 = (size_t)(row0 + l15);
  size_t rA1 = (size_t)(row0 + 16 + l15);
  const u32* wb = Wt + (size_t)l15 * 192 + g * 4;

  f32x4 acc[2][8];
  #pragma unroll
  for (int mi = 0; mi < 2; ++mi)
    #pragma unroll
    for (int nj = 0; nj < 8; ++nj) acc[mi][nj] = (f32x4){0.f, 0.f, 0.f, 0.f};

  gemm_phase(X0b + g * 4, rA0, rA1, wb, acc);
  gemm_phase(X1b + g * 4, rA0, rA1, wb + 64, acc);
  gemm_phase(X2b + g * 4, rA0, rA1, wb + 128, acc);

  float cs[8], cq[8];
  #pragma unroll
  for (int nj = 0; nj < 8; ++nj) { cs[nj] = 0.f; cq[nj] = 0.f; }
  if (active) {
    float bs[8];
    #pragma unroll
    for (int nj = 0; nj < 8; ++nj) bs[nj] = bias[nj * 16 + l15];
    #pragma unroll
    for (int mi = 0; mi < 2; ++mi) {
      #pragma unroll
      for (int r = 0; r < 4; ++r) {
        int row = row0 + mi * 16 + g * 4 + r;
        float sn = snorm[row];
        #pragma unroll
        for (int nj = 0; nj < 8; ++nj) {
          float h = (acc[mi][nj][r] + bs[nj]) * sn;
          out[(size_t)row * DIM + nj * 16 + l15] = h;
          cs[nj] += h;
          cq[nj] += h * h;
        }
      }
    }
  }
  ls[tid] = 0.f;
  __syncthreads();
  if (active) {
    #pragma unroll
    for (int nj = 0; nj < 8; ++nj) {
      atomicAdd(&ls[nj * 16 + l15], cs[nj]);
      atomicAdd(&ls[128 + nj * 16 + l15], cq[nj]);
    }
  }
  __syncthreads();
  if (tid < 128) {
    atomicAdd(&gsum[tid], ls[tid]);
    atomicAdd(&gsq[tid], ls[128 + tid]);
  }
}

// ---------------- BN prep + apply ----------------
__global__ void k_bnprep(const float* __restrict__ gsum, const float* __restrict__ gsq,
                         const float* __restrict__ gamma, const float* __restrict__ beta,
                         float* __restrict__ scale, float* __restrict__ shift) {
  int c = threadIdx.x;
  if (c < DIM) {
    float mean = gsum[c] * (1.0f / NN);
    float var = gsq[c] * (1.0f / NN) - mean * mean;
    var = fmaxf(var, 0.f);
    float sc = gamma[c] * rsqrtf(var + 1e-5f);
    scale[c] = sc;
    shift[c] = beta[c] - mean * sc;
  }
}

__global__ void k_apply(float* __restrict__ out, const float* __restrict__ scale,
                        const float* __restrict__ shift) {
  const int total4 = NN * DIM / 4;
  int i = blockIdx.x * blockDim.x + threadIdx.x;
  int st = gridDim.x * blockDim.x;
  for (int i4 = i; i4 < total4; i4 += st) {
    int c4 = (i4 & 31) * 4;
    float4 v = ((float4*)out)[i4];
    float4 s = *(const float4*)(scale + c4);
    float4 sh = *(const float4*)(shift + c4);
    v.x = fmaxf(fmaf(v.x, s.x, sh.x), 0.f);
    v.y = fmaxf(fmaf(v.y, s.y, sh.y), 0.f);
    v.z = fmaxf(fmaf(v.z, s.z, sh.z), 0.f);
    v.w = fmaxf(fmaf(v.w, s.w, sh.w), 0.f);
    ((float4*)out)[i4] = v;
  }
}

extern "C" void kernel_launch(void* const* d_in, const int* in_sizes, int n_in,
                              void* d_out, int out_size, void* d_ws, size_t ws_size,
                              hipStream_t stream) {
  const float* feature = (const float*)d_in[0];
  const float* snorm   = (const float*)d_in[1];
  const int*   src     = (const int*)d_in[2];
  const int*   dst     = (const int*)d_in[3];
  const float* W       = (const float*)d_in[4];
  const float* bias    = (const float*)d_in[5];
  const float* gamma   = (const float*)d_in[6];
  const float* beta    = (const float*)d_in[7];
  float* out = (float*)d_out;

  const size_t TBL = (size_t)NN * 64 * sizeof(u32);  // 25.6 MB
  char* p = (char*)d_ws;
  u32* X0b = (u32*)p; p += TBL;
  u32* Y0  = (u32*)p; p += TBL;   // reused as X2b after prop1 consumes it
  u32* X1b = (u32*)p; p += TBL;   // epair (12.8 MB) aliases this until k_fine done
  u32* Y1  = (u32*)p; p += TBL;
  u32* X2b = Y0;
  int2* epair = (int2*)X1b;
  u32* Wt  = (u32*)p; p += 128 * 192 * sizeof(u32);  // 98.3 KB
  int* esrc = (int*)p;    p += (size_t)EE * 4;
  int* rp   = (int*)p;    p += ((size_t)(NN + 1) * 4 + 127) & ~(size_t)127;
  float* ds = (float*)p;  p += (size_t)NN * 4;
  int* hist_t   = (int*)p; p += (size_t)NBUCK * B1 * 4;  // 200 KB
  int* blockoff = (int*)p; p += (size_t)NBUCK * B1 * 4;  // 200 KB
  int* btot  = (int*)p;   p += 512 * 4;
  int* bbase = (int*)p;   p += 512 * 4;
  char* zbeg = p;
  float* gsum = (float*)p; p += 512;
  float* gsq  = (float*)p; p += 512;
  float* scale = (float*)p; p += 512;
  float* shift = (float*)p; p += 512;

  hipMemsetAsync(zbeg, 0, 1024, stream);  // gsum, gsq

  k_hist<<<B1, 256, 0, stream>>>(dst, hist_t);
  k_boff<<<NBUCK, B1, 0, stream>>>(hist_t, blockoff, btot);
  k_bbase<<<1, 512, 0, stream>>>(btot, bbase);
  k_bucket<<<B1, 256, 0, stream>>>(src, dst, bbase, blockoff, epair);
  k_fine<<<NBUCK, 256, 0, stream>>>(epair, bbase, rp, ds, esrc);
  k_prep<<<4096, 256, 0, stream>>>(feature, ds, X0b, Y0);
  k_wprep<<<96, 256, 0, stream>>>(W, Wt);
  k_prop1<<<NN / 4, 256, 0, stream>>>(Y0, ds, rp, esrc, X1b, Y1);
  k_prop2<<<NN / 4, 256, 0, stream>>>(Y1, X0b, ds, rp, esrc, X2b);
  {
    int nwaves = NN / 32;  // 3125
    int nblk = (nwaves + 3) / 4;  // 782
    k_gemm<<<nblk, 256, 0, stream>>>(X0b, X1b, X2b, Wt, bias, snorm, out, gsum, gsq);
  }
  k_bnprep<<<1, 128, 0, stream>>>(gsum, gsq, gamma, beta, scale, shift);
  k_apply<<<4096, 256, 0, stream>>>(out, scale, shift);
}

// Round 6
// 301.078 us; speedup vs baseline: 2.9408x; 1.1244x over previous
//
#include <hip/hip_runtime.h>

#define NN 100000
#define EE 1600000
#define DIM 128
#define NBUCK ((NN + 255) >> 8)   // 391 buckets of 256 nodes
#define B1 128                    // bucket-pass blocks
#define CH ((EE + B1 - 1) / B1)   // 12500 edges per block

typedef unsigned int u32;
typedef __attribute__((ext_vector_type(8))) short bf16x8;
typedef __attribute__((ext_vector_type(4))) float f32x4;

union U4 { uint4 u; bf16x8 h; };

__device__ __forceinline__ float lof(u32 u) { return __uint_as_float(u << 16); }
__device__ __forceinline__ float hif(u32 u) { return __uint_as_float(u & 0xffff0000u); }
__device__ __forceinline__ u32 pack_bf2(float a, float b) {
  u32 ua = __float_as_uint(a), ub = __float_as_uint(b);
  ua = (ua + 0x7fffu + ((ua >> 16) & 1u)) >> 16;
  ub = (ub + 0x7fffu + ((ub >> 16) & 1u)) & 0xffff0000u;
  return ua | ub;
}

// ---------------- pass A: per-block bucket histogram ----------------
__global__ __launch_bounds__(256) void k_hist(const int* __restrict__ dst,
                                              int* __restrict__ hist_t) {
  __shared__ int h[NBUCK];
  for (int i = threadIdx.x; i < NBUCK; i += 256) h[i] = 0;
  __syncthreads();
  int e0 = blockIdx.x * CH;
  int e1 = e0 + CH < EE ? e0 + CH : EE;
  for (int e = e0 + threadIdx.x; e < e1; e += 256)
    atomicAdd(&h[dst[e] >> 8], 1);
  __syncthreads();
  for (int i = threadIdx.x; i < NBUCK; i += 256)
    hist_t[i * B1 + blockIdx.x] = h[i];
}

// ---------------- pass B: per-bucket scan over blocks ----------------
__global__ __launch_bounds__(B1) void k_boff(const int* __restrict__ hist_t,
                                             int* __restrict__ blockoff,
                                             int* __restrict__ btot) {
  __shared__ int ps[B1];
  int j = blockIdx.x, t = threadIdx.x;
  int v = hist_t[j * B1 + t];
  ps[t] = v;
  __syncthreads();
  #pragma unroll
  for (int off = 1; off < B1; off <<= 1) {
    int u = (t >= off) ? ps[t - off] : 0;
    __syncthreads();
    ps[t] += u;
    __syncthreads();
  }
  blockoff[j * B1 + t] = ps[t] - v;
  if (t == B1 - 1) btot[j] = ps[t];
}

// ---------------- pass B2: scan bucket totals -> bbase ----------------
__global__ __launch_bounds__(512) void k_bbase(const int* __restrict__ btot,
                                               int* __restrict__ bbase) {
  __shared__ int ps[512];
  int t = threadIdx.x;
  int v = (t < NBUCK) ? btot[t] : 0;
  ps[t] = v;
  __syncthreads();
  #pragma unroll
  for (int off = 1; off < 512; off <<= 1) {
    int u = (t >= off) ? ps[t - off] : 0;
    __syncthreads();
    ps[t] += u;
    __syncthreads();
  }
  if (t < NBUCK) bbase[t] = ps[t] - v;
  if (t == 0) bbase[NBUCK] = EE;
}

// ---------------- pass C: scatter (dst,src) pairs into bucket regions ----------------
__global__ __launch_bounds__(256) void k_bucket(const int* __restrict__ src,
                                                const int* __restrict__ dst,
                                                const int* __restrict__ bbase,
                                                const int* __restrict__ blockoff,
                                                int2* __restrict__ epair) {
  __shared__ int cnt[NBUCK];
  for (int i = threadIdx.x; i < NBUCK; i += 256) cnt[i] = 0;
  __syncthreads();
  int e0 = blockIdx.x * CH;
  int e1 = e0 + CH < EE ? e0 + CH : EE;
  for (int e = e0 + threadIdx.x; e < e1; e += 256) {
    int d = dst[e], s = src[e];
    int j = d >> 8;
    int loc = atomicAdd(&cnt[j], 1);
    epair[bbase[j] + blockoff[j * B1 + blockIdx.x] + loc] = make_int2(d, s);
  }
}

// ---------------- pass D: per-bucket deg/ds/rp + fine scatter -> esrc ----------------
__global__ __launch_bounds__(256) void k_fine(const int2* __restrict__ epair,
                                              const int* __restrict__ bbase,
                                              int* __restrict__ rp,
                                              float* __restrict__ ds,
                                              int* __restrict__ esrc) {
  __shared__ int cntA[256], cntB[256], rpl[256], ps[256];
  int j = blockIdx.x, t = threadIdx.x;
  int node0 = j << 8;
  int e0 = bbase[j], e1 = bbase[j + 1];
  cntA[t] = 0;
  cntB[t] = 0;
  __syncthreads();
  for (int e = e0 + t; e < e1; e += 256)
    atomicAdd(&cntA[epair[e].x & 255], 1);
  __syncthreads();
  int deg = cntA[t];
  ps[t] = deg;
  __syncthreads();
  #pragma unroll
  for (int off = 1; off < 256; off <<= 1) {
    int u = (t >= off) ? ps[t - off] : 0;
    __syncthreads();
    ps[t] += u;
    __syncthreads();
  }
  rpl[t] = e0 + ps[t] - deg;
  __syncthreads();
  int node = node0 + t;
  if (node < NN) {
    rp[node] = rpl[t];
    ds[node] = rsqrtf(fmaxf((float)deg, 1.0f));
  }
  if (j == 0 && t == 0) rp[NN] = EE;
  for (int e = e0 + t; e < e1; e += 256) {
    int2 pr = epair[e];
    int d = pr.x & 255;
    int pos = rpl[d] + atomicAdd(&cntB[d], 1);
    esrc[pos] = pr.y;
  }
}

// ---------------- prep: X0b = bf16(feature), Y0 = bf16(feature*ds) ----------------
__global__ void k_prep(const float* __restrict__ feature, const float* __restrict__ ds,
                       u32* __restrict__ X0b, u32* __restrict__ Y0) {
  const int total = NN * 32;  // uint2 count (4 dims each)
  int i = blockIdx.x * blockDim.x + threadIdx.x;
  int st = gridDim.x * blockDim.x;
  for (int j = i; j < total; j += st) {
    int n = j >> 5;
    float4 f = *(const float4*)(feature + (size_t)n * DIM + (j & 31) * 4);
    float dsn = ds[n];
    ((uint2*)X0b)[j] = make_uint2(pack_bf2(f.x, f.y), pack_bf2(f.z, f.w));
    ((uint2*)Y0)[j] = make_uint2(pack_bf2(f.x * dsn, f.y * dsn),
                                 pack_bf2(f.z * dsn, f.w * dsn));
  }
}

// ---------------- W -> bf16 fragment-major layout Wf ----------------
// Wf u32 index = ((phase*4+ks)*8+nj)*256 + lane*4 + j
// lane = g*16+l15 holds column n = nj*16+l15, u32 k-chunk phase*64+ks*16+g*4+j
__global__ void k_wprep(const float* __restrict__ W, u32* __restrict__ Wf) {
  int idx = blockIdx.x * blockDim.x + threadIdx.x;
  if (idx >= 96 * 256) return;
  int fi = idx >> 8;              // fragment 0..95
  int lane = (idx >> 2) & 63;
  int j = idx & 3;
  int phase = fi >> 5, ks = (fi >> 3) & 3, nj = fi & 7;
  int g = lane >> 4, l15 = lane & 15;
  int n = nj * 16 + l15;
  int ku = phase * 64 + ks * 16 + g * 4 + j;
  int k = ku * 2;
  float w0 = W[(size_t)k * 128 + n];
  float w1 = W[(size_t)(k + 1) * 128 + n];
  Wf[idx] = pack_bf2(w0, w1);
}

// ---------------- prop1: X1 = -ds[n]*sum Y0[s]; write X1b, Y1 = X1*ds[n] ----------------
__global__ __launch_bounds__(256) void k_prop1(const u32* __restrict__ Y0,
                                               const float* __restrict__ ds,
                                               const int* __restrict__ rp,
                                               const int* __restrict__ esrc,
                                               u32* __restrict__ X1b,
                                               u32* __restrict__ Y1) {
  int n = blockIdx.x * 4 + (threadIdx.x >> 6);
  int l = threadIdx.x & 63;
  int beg = rp[n], end = rp[n + 1];
  float a0x = 0, a0y = 0, a1x = 0, a1y = 0, a2x = 0, a2y = 0, a3x = 0, a3y = 0;
  int p = beg;
  for (; p + 4 <= end; p += 4) {
    int s0 = esrc[p], s1 = esrc[p + 1], s2 = esrc[p + 2], s3 = esrc[p + 3];
    u32 u0 = Y0[(size_t)s0 * 64 + l];
    u32 u1 = Y0[(size_t)s1 * 64 + l];
    u32 u2 = Y0[(size_t)s2 * 64 + l];
    u32 u3 = Y0[(size_t)s3 * 64 + l];
    a0x += lof(u0); a0y += hif(u0);
    a1x += lof(u1); a1y += hif(u1);
    a2x += lof(u2); a2y += hif(u2);
    a3x += lof(u3); a3y += hif(u3);
  }
  for (; p < end; ++p) {
    u32 u = Y0[(size_t)esrc[p] * 64 + l];
    a0x += lof(u); a0y += hif(u);
  }
  float dsn = ds[n];
  float x = -dsn * ((a0x + a1x) + (a2x + a3x));
  float y = -dsn * ((a0y + a1y) + (a2y + a3y));
  X1b[(size_t)n * 64 + l] = pack_bf2(x, y);
  Y1[(size_t)n * 64 + l] = pack_bf2(x * dsn, y * dsn);
}

// ---------------- prop2: X2 = -2*ds[n]*sum Y1[s] - X0 ----------------
__global__ __launch_bounds__(256) void k_prop2(const u32* __restrict__ Y1,
                                               const u32* __restrict__ X0b,
                                               const float* __restrict__ ds,
                                               const int* __restrict__ rp,
                                               const int* __restrict__ esrc,
                                               u32* __restrict__ X2b) {
  int n = blockIdx.x * 4 + (threadIdx.x >> 6);
  int l = threadIdx.x & 63;
  int beg = rp[n], end = rp[n + 1];
  float a0x = 0, a0y = 0, a1x = 0, a1y = 0, a2x = 0, a2y = 0, a3x = 0, a3y = 0;
  int p = beg;
  for (; p + 4 <= end; p += 4) {
    int s0 = esrc[p], s1 = esrc[p + 1], s2 = esrc[p + 2], s3 = esrc[p + 3];
    u32 u0 = Y1[(size_t)s0 * 64 + l];
    u32 u1 = Y1[(size_t)s1 * 64 + l];
    u32 u2 = Y1[(size_t)s2 * 64 + l];
    u32 u3 = Y1[(size_t)s3 * 64 + l];
    a0x += lof(u0); a0y += hif(u0);
    a1x += lof(u1); a1y += hif(u1);
    a2x += lof(u2); a2y += hif(u2);
    a3x += lof(u3); a3y += hif(u3);
  }
  for (; p < end; ++p) {
    u32 u = Y1[(size_t)esrc[p] * 64 + l];
    a0x += lof(u); a0y += hif(u);
  }
  float dsn = ds[n];
  u32 u0 = X0b[(size_t)n * 64 + l];
  float x = -2.0f * dsn * ((a0x + a1x) + (a2x + a3x)) - lof(u0);
  float y = -2.0f * dsn * ((a0y + a1y) + (a2y + a3y)) - hif(u0);
  X2b[(size_t)n * 64 + l] = pack_bf2(x, y);
}

// ---------------- MFMA GEMM with LDS-staged fragment-major W ----------------
// 1024 threads = 16 waves x 32 rows = 512 rows/block; 196 blocks (1 round).
// B-frag ds_read is lane-linear (frag*1024B + lane*16B) -> conflict-free.
__global__ __launch_bounds__(1024) void k_gemm(const u32* __restrict__ X0b,
                                               const u32* __restrict__ X1b,
                                               const u32* __restrict__ X2b,
                                               const u32* __restrict__ Wf,
                                               const float* __restrict__ bias,
                                               const float* __restrict__ snorm,
                                               float* __restrict__ out,
                                               float* __restrict__ gsum,
                                               float* __restrict__ gsq) {
  __shared__ u32 wlds[24576];   // 96 KB
  __shared__ float ls[256];
  int tid = threadIdx.x;
  // stage Wf linearly: 6144 uint4 by 1024 threads
  #pragma unroll
  for (int l = 0; l < 6; ++l) {
    int it = tid + l * 1024;
    ((uint4*)wlds)[it] = ((const uint4*)Wf)[it];
  }
  int wid = tid >> 6, lane = tid & 63;
  int l15 = lane & 15, g = lane >> 4;
  int row0 = blockIdx.x * 512 + wid * 32;
  bool active = (row0 + 32) <= NN;
  if (!active) row0 = 0;

  size_t rb0 = (size_t)(row0 + l15) * 64 + g * 4;
  size_t rb1 = rb0 + (size_t)16 * 64;

  f32x4 acc[2][8];
  #pragma unroll
  for (int mi = 0; mi < 2; ++mi)
    #pragma unroll
    for (int nj = 0; nj < 8; ++nj) acc[mi][nj] = (f32x4){0.f, 0.f, 0.f, 0.f};

  __syncthreads();

  const u32* tabs[3] = {X0b, X1b, X2b};
  #pragma unroll
  for (int phase = 0; phase < 3; ++phase) {
    const u32* A = tabs[phase];
    #pragma unroll
    for (int ks = 0; ks < 4; ++ks) {
      U4 a0, a1;
      a0.u = *(const uint4*)(A + rb0 + ks * 16);
      a1.u = *(const uint4*)(A + rb1 + ks * 16);
      #pragma unroll
      for (int nj = 0; nj < 8; ++nj) {
        U4 b;
        b.u = ((const uint4*)wlds)[((phase * 4 + ks) * 8 + nj) * 64 + lane];
        acc[0][nj] = __builtin_amdgcn_mfma_f32_16x16x32_bf16(a0.h, b.h, acc[0][nj], 0, 0, 0);
        acc[1][nj] = __builtin_amdgcn_mfma_f32_16x16x32_bf16(a1.h, b.h, acc[1][nj], 0, 0, 0);
      }
    }
  }

  float cs[8], cq[8];
  #pragma unroll
  for (int nj = 0; nj < 8; ++nj) { cs[nj] = 0.f; cq[nj] = 0.f; }
  if (active) {
    float bs[8];
    #pragma unroll
    for (int nj = 0; nj < 8; ++nj) bs[nj] = bias[nj * 16 + l15];
    #pragma unroll
    for (int mi = 0; mi < 2; ++mi) {
      #pragma unroll
      for (int r = 0; r < 4; ++r) {
        int row = row0 + mi * 16 + g * 4 + r;
        float sn = snorm[row];
        #pragma unroll
        for (int nj = 0; nj < 8; ++nj) {
          float h = (acc[mi][nj][r] + bs[nj]) * sn;
          out[(size_t)row * DIM + nj * 16 + l15] = h;
          cs[nj] += h;
          cq[nj] += h * h;
        }
      }
    }
  }
  if (tid < 256) ls[tid] = 0.f;
  __syncthreads();
  if (active) {
    #pragma unroll
    for (int nj = 0; nj < 8; ++nj) {
      atomicAdd(&ls[nj * 16 + l15], cs[nj]);
      atomicAdd(&ls[128 + nj * 16 + l15], cq[nj]);
    }
  }
  __syncthreads();
  if (tid < 128) {
    atomicAdd(&gsum[tid], ls[tid]);
    atomicAdd(&gsq[tid], ls[128 + tid]);
  }
}

// ---------------- BN prep + apply ----------------
__global__ void k_bnprep(const float* __restrict__ gsum, const float* __restrict__ gsq,
                         const float* __restrict__ gamma, const float* __restrict__ beta,
                         float* __restrict__ scale, float* __restrict__ shift) {
  int c = threadIdx.x;
  if (c < DIM) {
    float mean = gsum[c] * (1.0f / NN);
    float var = gsq[c] * (1.0f / NN) - mean * mean;
    var = fmaxf(var, 0.f);
    float sc = gamma[c] * rsqrtf(var + 1e-5f);
    scale[c] = sc;
    shift[c] = beta[c] - mean * sc;
  }
}

__global__ void k_apply(float* __restrict__ out, const float* __restrict__ scale,
                        const float* __restrict__ shift) {
  const int total4 = NN * DIM / 4;
  int i = blockIdx.x * blockDim.x + threadIdx.x;
  int st = gridDim.x * blockDim.x;
  for (int i4 = i; i4 < total4; i4 += st) {
    int c4 = (i4 & 31) * 4;
    float4 v = ((float4*)out)[i4];
    float4 s = *(const float4*)(scale + c4);
    float4 sh = *(const float4*)(shift + c4);
    v.x = fmaxf(fmaf(v.x, s.x, sh.x), 0.f);
    v.y = fmaxf(fmaf(v.y, s.y, sh.y), 0.f);
    v.z = fmaxf(fmaf(v.z, s.z, sh.z), 0.f);
    v.w = fmaxf(fmaf(v.w, s.w, sh.w), 0.f);
    ((float4*)out)[i4] = v;
  }
}

extern "C" void kernel_launch(void* const* d_in, const int* in_sizes, int n_in,
                              void* d_out, int out_size, void* d_ws, size_t ws_size,
                              hipStream_t stream) {
  const float* feature = (const float*)d_in[0];
  const float* snorm   = (const float*)d_in[1];
  const int*   src     = (const int*)d_in[2];
  const int*   dst     = (const int*)d_in[3];
  const float* W       = (const float*)d_in[4];
  const float* bias    = (const float*)d_in[5];
  const float* gamma   = (const float*)d_in[6];
  const float* beta    = (const float*)d_in[7];
  float* out = (float*)d_out;

  const size_t TBL = (size_t)NN * 64 * sizeof(u32);  // 25.6 MB
  char* p = (char*)d_ws;
  u32* X0b = (u32*)p; p += TBL;
  u32* Y0  = (u32*)p; p += TBL;   // reused as X2b after prop1 consumes it
  u32* X1b = (u32*)p; p += TBL;   // epair (12.8 MB) aliases this until k_fine done
  u32* Y1  = (u32*)p; p += TBL;
  u32* X2b = Y0;
  int2* epair = (int2*)X1b;
  u32* Wf  = (u32*)p; p += 96 * 256 * sizeof(u32);   // 98.3 KB
  int* esrc = (int*)p;    p += (size_t)EE * 4;
  int* rp   = (int*)p;    p += ((size_t)(NN + 1) * 4 + 127) & ~(size_t)127;
  float* ds = (float*)p;  p += (size_t)NN * 4;
  int* hist_t   = (int*)p; p += (size_t)NBUCK * B1 * 4;  // 200 KB
  int* blockoff = (int*)p; p += (size_t)NBUCK * B1 * 4;  // 200 KB
  int* btot  = (int*)p;   p += 512 * 4;
  int* bbase = (int*)p;   p += 512 * 4;
  char* zbeg = p;
  float* gsum = (float*)p; p += 512;
  float* gsq  = (float*)p; p += 512;
  float* scale = (float*)p; p += 512;
  float* shift = (float*)p; p += 512;

  hipMemsetAsync(zbeg, 0, 1024, stream);  // gsum, gsq

  k_hist<<<B1, 256, 0, stream>>>(dst, hist_t);
  k_boff<<<NBUCK, B1, 0, stream>>>(hist_t, blockoff, btot);
  k_bbase<<<1, 512, 0, stream>>>(btot, bbase);
  k_bucket<<<B1, 256, 0, stream>>>(src, dst, bbase, blockoff, epair);
  k_fine<<<NBUCK, 256, 0, stream>>>(epair, bbase, rp, ds, esrc);
  k_prep<<<4096, 256, 0, stream>>>(feature, ds, X0b, Y0);
  k_wprep<<<96, 256, 0, stream>>>(W, Wf);
  k_prop1<<<NN / 4, 256, 0, stream>>>(Y0, ds, rp, esrc, X1b, Y1);
  k_prop2<<<NN / 4, 256, 0, stream>>>(Y1, X0b, ds, rp, esrc, X2b);
  k_gemm<<<(NN + 511) / 512, 1024, 0, stream>>>(X0b, X1b, X2b, Wf, bias, snorm,
                                                out, gsum, gsq);
  k_bnprep<<<1, 128, 0, stream>>>(gsum, gsq, gamma, beta, scale, shift);
  k_apply<<<4096, 256, 0, stream>>>(out, scale, shift);
}